// Round 2
// baseline (2998.686 us; speedup 1.0000x reference)
//
#include <hip/hip_runtime.h>
#include <hip/hip_bf16.h>

#define N_NODES 50000
#define NREL 16
#define HID 64
#define NCLS 16
#define EPW 64   // edges per wave in the edge kernels

// ---------------------------------------------------------------------------
// ws layout (floats): cnt[16*50000] | histRel[16](int) | bounds[20](int,17 used)
//                     | cursor[16](int) | X1[50000*64] | ssrc[E](int)
//                     | sdst[E](int) | sinv[E]
// prefix before X1 = 800000+16+20+16 = 800052 elems (16B aligned)
// ---------------------------------------------------------------------------

// K1: histogram over relations (LDS-reduced) + per-(rel,dst) edge counts
__global__ __launch_bounds__(256) void hist_k(const int* __restrict__ dstp,
                                              const int* __restrict__ et,
                                              float* __restrict__ cnt,
                                              int* __restrict__ histRel, int E) {
    __shared__ int hr[NREL];
    if (threadIdx.x < NREL) hr[threadIdx.x] = 0;
    __syncthreads();
    int i = blockIdx.x * 256 + threadIdx.x;
    if (i < E) {
        int r = et[i];
        atomicAdd(&hr[r], 1);
        unsafeAtomicAdd(&cnt[(size_t)r * N_NODES + dstp[i]], 1.0f);
    }
    __syncthreads();
    if (threadIdx.x < NREL && hr[threadIdx.x] > 0)
        atomicAdd(&histRel[threadIdx.x], hr[threadIdx.x]);
}

// K2: tiny exclusive prefix over 16 relation counts -> bounds[0..16], cursor
__global__ void scan_k(const int* __restrict__ histRel,
                       int* __restrict__ bounds, int* __restrict__ cursor) {
    if (threadIdx.x == 0) {
        int acc = 0;
        for (int r = 0; r < NREL; ++r) {
            bounds[r] = acc;
            cursor[r] = acc;
            acc += histRel[r];
        }
        bounds[NREL] = acc;
    }
}

// K3: ranked scatter into relation buckets. Per wave per relation: one
// cursor atomic for the whole group, lanes write at base+rank (coalesced).
__global__ __launch_bounds__(256) void scatter_k(const int* __restrict__ srcp,
                                                 const int* __restrict__ dstp,
                                                 const int* __restrict__ et,
                                                 const float* __restrict__ cnt,
                                                 int* __restrict__ cursor,
                                                 int* __restrict__ ssrc,
                                                 int* __restrict__ sdst,
                                                 float* __restrict__ sinv, int E) {
    int i = blockIdx.x * 256 + threadIdx.x;
    int lane = threadIdx.x & 63;
    bool valid = (i < E);
    int t = valid ? et[i] : -1;
    int s = valid ? srcp[i] : 0;
    int dd = valid ? dstp[i] : 0;
    unsigned long long ltmask = (lane == 0) ? 0ull : ((~0ull) >> (64 - lane));
#pragma unroll
    for (int r = 0; r < NREL; ++r) {
        unsigned long long m = __ballot(t == r);
        if (m == 0) continue;
        int n = __popcll(m);
        int leader = __ffsll(m) - 1;
        int myrank = __popcll(m & ltmask);
        int pos0 = 0;
        if (lane == leader) pos0 = atomicAdd(&cursor[r], n);
        pos0 = __shfl(pos0, leader, 64);
        if (t == r) {
            int p = pos0 + myrank;
            ssrc[p] = s;
            sdst[p] = dd;
            sinv[p] = 1.0f / cnt[(size_t)r * N_NODES + dd];
        }
    }
}

// K4: X1 = x @ root1 + b1   (one wave per node, lane = out dim)
__global__ __launch_bounds__(256) void init1(const float* __restrict__ x,
                                             const float* __restrict__ root1,
                                             const float* __restrict__ b1,
                                             float* __restrict__ X1) {
    int gid = blockIdx.x * 256 + threadIdx.x;
    int node = gid >> 6;
    int d = gid & 63;
    if (node >= N_NODES) return;
    const float* xr = x + (size_t)node * HID;
    float h0 = b1[d], h1 = 0.f, h2 = 0.f, h3 = 0.f;
#pragma unroll
    for (int k = 0; k < HID; k += 4) {
        h0 = fmaf(xr[k + 0], root1[(k + 0) * HID + d], h0);
        h1 = fmaf(xr[k + 1], root1[(k + 1) * HID + d], h1);
        h2 = fmaf(xr[k + 2], root1[(k + 2) * HID + d], h2);
        h3 = fmaf(xr[k + 3], root1[(k + 3) * HID + d], h3);
    }
    X1[(size_t)node * HID + d] = (h0 + h1) + (h2 + h3);
}

// K5: layer-1 edge scatter over SORTED edges. Wave owns EPW contiguous
// edges (relation-uniform except across <=15 global boundaries). Lane d
// holds W1[rel][:,d] in 64 VGPRs; per edge: uniform scalar loads of
// (src,dst,inv) + x row, 64 FMAs/lane, one contiguous 256B atomic scatter.
__global__ __launch_bounds__(256) void edge_l1s(const int* __restrict__ ssrc,
                                                const int* __restrict__ sdst,
                                                const float* __restrict__ sinv,
                                                const int* __restrict__ bounds,
                                                const float* __restrict__ x,
                                                const float* __restrict__ W1,
                                                float* __restrict__ X1, int E) {
    int wave = (blockIdx.x * 256 + threadIdx.x) >> 6;
    int lane = threadIdx.x & 63;
    int start = wave * EPW;
    if (start >= E) return;
    int end = start + EPW;
    if (end > E) end = E;

    int rel = 0;
    while (bounds[rel + 1] <= start) ++rel;
    int relEnd = bounds[rel + 1];

    float Wc[HID];
#pragma unroll
    for (int k = 0; k < HID; ++k)
        Wc[k] = W1[(size_t)rel * HID * HID + (size_t)k * HID + lane];

    for (int e = start; e < end; ++e) {
        if (e >= relEnd) {
            do { ++rel; relEnd = bounds[rel + 1]; } while (relEnd <= e);
#pragma unroll
            for (int k = 0; k < HID; ++k)
                Wc[k] = W1[(size_t)rel * HID * HID + (size_t)k * HID + lane];
        }
        int s = ssrc[e];
        int dd = sdst[e];
        float inv = sinv[e];
        const float* xr = x + (size_t)s * HID;  // uniform -> scalar loads
        float h0 = 0.f, h1 = 0.f, h2 = 0.f, h3 = 0.f;
#pragma unroll
        for (int k = 0; k < HID; k += 4) {
            h0 = fmaf(xr[k + 0], Wc[k + 0], h0);
            h1 = fmaf(xr[k + 1], Wc[k + 1], h1);
            h2 = fmaf(xr[k + 2], Wc[k + 2], h2);
            h3 = fmaf(xr[k + 3], Wc[k + 3], h3);
        }
        float h = (h0 + h1) + (h2 + h3);
        unsafeAtomicAdd(&X1[(size_t)dd * HID + lane], h * inv);
    }
}

// K6: in-place ReLU on X1
__global__ __launch_bounds__(256) void relu_k(float* __restrict__ X1, int n) {
    int i = blockIdx.x * 256 + threadIdx.x;
    if (i < n) X1[i] = fmaxf(X1[i], 0.0f);
}

// K7: out = X1 @ root2 + b2   (thread per (node, class))
__global__ __launch_bounds__(256) void init2(const float* __restrict__ X1,
                                             const float* __restrict__ root2,
                                             const float* __restrict__ b2,
                                             float* __restrict__ out) {
    int gid = blockIdx.x * 256 + threadIdx.x;
    int node = gid >> 4;
    int d = gid & 15;
    if (node >= N_NODES) return;
    const float* xr = X1 + (size_t)node * HID;
    float h0 = b2[d], h1 = 0.f, h2 = 0.f, h3 = 0.f;
#pragma unroll
    for (int k = 0; k < HID; k += 4) {
        h0 = fmaf(xr[k + 0], root2[(k + 0) * NCLS + d], h0);
        h1 = fmaf(xr[k + 1], root2[(k + 1) * NCLS + d], h1);
        h2 = fmaf(xr[k + 2], root2[(k + 2) * NCLS + d], h2);
        h3 = fmaf(xr[k + 3], root2[(k + 3) * NCLS + d], h3);
    }
    out[(size_t)node * NCLS + d] = (h0 + h1) + (h2 + h3);
}

// K8: layer-2 edge scatter over SORTED edges. Lane = (q=lane>>4, d=lane&15);
// per edge: 4 float4 loads of the q-th row quarter, 16 FMAs, shfl_xor
// reduction over quarters, 16-lane contiguous atomic.
__global__ __launch_bounds__(256) void edge_l2s(const int* __restrict__ ssrc,
                                                const int* __restrict__ sdst,
                                                const float* __restrict__ sinv,
                                                const int* __restrict__ bounds,
                                                const float* __restrict__ X1,
                                                const float* __restrict__ W2,
                                                float* __restrict__ out, int E) {
    int wave = (blockIdx.x * 256 + threadIdx.x) >> 6;
    int lane = threadIdx.x & 63;
    int d = lane & 15;
    int q = lane >> 4;
    int start = wave * EPW;
    if (start >= E) return;
    int end = start + EPW;
    if (end > E) end = E;

    int rel = 0;
    while (bounds[rel + 1] <= start) ++rel;
    int relEnd = bounds[rel + 1];

    float Wc[16];
#pragma unroll
    for (int j = 0; j < 16; ++j)
        Wc[j] = W2[(size_t)rel * HID * NCLS + (size_t)(q * 16 + j) * NCLS + d];

    for (int e = start; e < end; ++e) {
        if (e >= relEnd) {
            do { ++rel; relEnd = bounds[rel + 1]; } while (relEnd <= e);
#pragma unroll
            for (int j = 0; j < 16; ++j)
                Wc[j] = W2[(size_t)rel * HID * NCLS + (size_t)(q * 16 + j) * NCLS + d];
        }
        int s = ssrc[e];
        int dd = sdst[e];
        float inv = sinv[e];
        const float4* xr4 = (const float4*)(X1 + (size_t)s * HID);
        float h = 0.f;
#pragma unroll
        for (int j4 = 0; j4 < 4; ++j4) {
            float4 xv = xr4[q * 4 + j4];
            h = fmaf(xv.x, Wc[j4 * 4 + 0], h);
            h = fmaf(xv.y, Wc[j4 * 4 + 1], h);
            h = fmaf(xv.z, Wc[j4 * 4 + 2], h);
            h = fmaf(xv.w, Wc[j4 * 4 + 3], h);
        }
        h += __shfl_xor(h, 16, 64);
        h += __shfl_xor(h, 32, 64);
        if (q == 0) {
            unsafeAtomicAdd(&out[(size_t)dd * NCLS + d], h * inv);
        }
    }
}

extern "C" void kernel_launch(void* const* d_in, const int* in_sizes, int n_in,
                              void* d_out, int out_size, void* d_ws, size_t ws_size,
                              hipStream_t stream) {
    const int* ei    = (const int*)d_in[0];   // [2, E]
    const int* et    = (const int*)d_in[1];   // [E]
    const float* x   = (const float*)d_in[2]; // [N, 64]
    const float* W1  = (const float*)d_in[3]; // [16, 64, 64]
    const float* r1  = (const float*)d_in[4]; // [64, 64]
    const float* b1  = (const float*)d_in[5]; // [64]
    const float* W2  = (const float*)d_in[6]; // [16, 64, 16]
    const float* r2  = (const float*)d_in[7]; // [64, 16]
    const float* b2  = (const float*)d_in[8]; // [16]
    float* out = (float*)d_out;               // [N, 16]

    int E = in_sizes[0] / 2;
    const int* srcp = ei;
    const int* dstp = ei + E;

    float* base = (float*)d_ws;
    float* cnt     = base;                               // 16*50000 f
    int*   histRel = (int*)(base + (size_t)NREL * N_NODES);      // 16 i
    int*   bounds  = histRel + 16;                       // 20 i (17 used)
    int*   cursor  = bounds + 20;                        // 16 i
    float* X1      = (float*)(cursor + 16);              // 50000*64 f (16B aligned)
    int*   ssrc    = (int*)(X1 + (size_t)N_NODES * HID); // E i
    int*   sdst    = ssrc + E;                           // E i
    float* sinv    = (float*)(sdst + E);                 // E f

    // zero cnt + histRel in one shot
    hipMemsetAsync(cnt, 0, ((size_t)NREL * N_NODES + 16) * sizeof(float), stream);

    int eb = (E + 255) / 256;
    hist_k<<<eb, 256, 0, stream>>>(dstp, et, cnt, histRel, E);
    scan_k<<<1, 64, 0, stream>>>(histRel, bounds, cursor);
    scatter_k<<<eb, 256, 0, stream>>>(srcp, dstp, et, cnt, cursor, ssrc, sdst, sinv, E);

    init1<<<(N_NODES * HID + 255) / 256, 256, 0, stream>>>(x, r1, b1, X1);

    int waves = (E + EPW - 1) / EPW;
    int blocks = (waves + 3) / 4;  // 4 waves per 256-thread block

    edge_l1s<<<blocks, 256, 0, stream>>>(ssrc, sdst, sinv, bounds, x, W1, X1, E);

    relu_k<<<(N_NODES * HID + 255) / 256, 256, 0, stream>>>(X1, N_NODES * HID);

    init2<<<(N_NODES * NCLS + 255) / 256, 256, 0, stream>>>(X1, r2, b2, out);

    edge_l2s<<<blocks, 256, 0, stream>>>(ssrc, sdst, sinv, bounds, X1, W2, out, E);
}

// Round 3
// 1125.927 us; speedup vs baseline: 2.6633x; 2.6633x over previous
//
#include <hip/hip_runtime.h>
#include <hip/hip_bf16.h>

#define N_NODES 50000
#define NREL 16
#define HID 64
#define NCLS 16

// ---------------------------------------------------------------------------
// ws layout (runtime offsets, G = relations per sweep from ws_size):
//   cnt/inv [16*50000] f32 | A [G*50000*64] f32 | blockHist [16*NB] i32
//   | bounds [32] i32 | sedge [E] int2 | X1 [50000*64] f32
// ---------------------------------------------------------------------------

// K1: per-block relation histogram (stored, no global atomics) + per-(rel,dst)
// edge counts.
__global__ __launch_bounds__(256) void hist_k(const int* __restrict__ dstp,
                                              const int* __restrict__ et,
                                              float* __restrict__ cnt,
                                              int* __restrict__ bh, int NB, int E) {
    __shared__ int hr[NREL];
    if (threadIdx.x < NREL) hr[threadIdx.x] = 0;
    __syncthreads();
    int i = blockIdx.x * 256 + threadIdx.x;
    if (i < E) {
        int r = et[i];
        atomicAdd(&hr[r], 1);
        unsafeAtomicAdd(&cnt[(size_t)r * N_NODES + dstp[i]], 1.0f);
    }
    __syncthreads();
    if (threadIdx.x < NREL) bh[threadIdx.x * NB + blockIdx.x] = hr[threadIdx.x];
}

// K2: device scan. 16 waves; wave r turns blockHist[r][:] into global
// per-block base offsets (in place) and writes bounds[0..16].
__global__ __launch_bounds__(1024) void scan_k(int* __restrict__ bh,
                                               int* __restrict__ bounds, int NB) {
    __shared__ int relTot[NREL];
    __shared__ int relBase[NREL + 1];
    int wid = threadIdx.x >> 6, lane = threadIdx.x & 63;
    int sum = 0;
    for (int c = lane; c < NB; c += 64) sum += bh[wid * NB + c];
#pragma unroll
    for (int off = 1; off < 64; off <<= 1) sum += __shfl_xor(sum, off, 64);
    if (lane == 0) relTot[wid] = sum;
    __syncthreads();
    if (threadIdx.x == 0) {
        int a = 0;
        for (int r = 0; r < NREL; ++r) { relBase[r] = a; a += relTot[r]; }
        relBase[NREL] = a;
    }
    __syncthreads();
    int run = relBase[wid];
    for (int c0 = 0; c0 < NB; c0 += 64) {
        int idx = c0 + lane;
        int v = (idx < NB) ? bh[wid * NB + idx] : 0;
        int x = v;
#pragma unroll
        for (int off = 1; off < 64; off <<= 1) {
            int y = __shfl_up(x, off, 64);
            if (lane >= off) x += y;
        }
        if (idx < NB) bh[wid * NB + idx] = run + (x - v);
        run += __shfl(x, 63, 64);
    }
    if (threadIdx.x < NREL + 1) bounds[threadIdx.x] = relBase[threadIdx.x];
}

// K3: scatter with per-block LDS cursors (no contended global atomics).
__global__ __launch_bounds__(256) void scatter_k2(const int* __restrict__ srcp,
                                                  const int* __restrict__ dstp,
                                                  const int* __restrict__ et,
                                                  const int* __restrict__ bh,
                                                  int2* __restrict__ sedge,
                                                  int NB, int E) {
    __shared__ int cur[NREL];
    if (threadIdx.x < NREL) cur[threadIdx.x] = bh[threadIdx.x * NB + blockIdx.x];
    __syncthreads();
    int i = blockIdx.x * 256 + threadIdx.x;
    if (i < E) {
        int r = et[i];
        int p = atomicAdd(&cur[r], 1);
        sedge[p] = make_int2(srcp[i], dstp[i]);
    }
}

// K4: cnt -> inv in place (0 where no edges: kills NaN and zeroes contribs)
__global__ __launch_bounds__(256) void inv_k(float* __restrict__ cnt, int n) {
    int i = blockIdx.x * 256 + threadIdx.x;
    if (i < n) {
        float v = cnt[i];
        cnt[i] = (v > 0.0f) ? (1.0f / v) : 0.0f;
    }
}

// K5: aggregation. Grid-stride waves over sorted bucket [bounds[r0], bounds[r0+gcnt]).
// One wave per edge-step: uniform s_load meta, 256B coalesced gather of the
// feature row (optionally relu'd), 256B atomic add into A[rel_local][dst].
__global__ __launch_bounds__(256) void agg_k(const int2* __restrict__ sedge,
                                             const int* __restrict__ bounds,
                                             const float* __restrict__ feat,
                                             float* __restrict__ A,
                                             int r0, int gcnt, int relu) {
    int wgid = __builtin_amdgcn_readfirstlane((blockIdx.x * 256 + threadIdx.x) >> 6);
    int lane = threadIdx.x & 63;
    int lo = bounds[r0], hi = bounds[r0 + gcnt];
    int nw = (gridDim.x * 256) >> 6;
    int len = hi - lo;
    int c = (len + nw - 1) / nw;
    int e = lo + wgid * c;
    int end = e + c;
    if (end > hi) end = hi;

    for (; e + 3 < end; e += 4) {
        int2 s0 = sedge[e], s1 = sedge[e + 1], s2 = sedge[e + 2], s3 = sedge[e + 3];
        float v0 = feat[(size_t)s0.x * HID + lane];
        float v1 = feat[(size_t)s1.x * HID + lane];
        float v2 = feat[(size_t)s2.x * HID + lane];
        float v3 = feat[(size_t)s3.x * HID + lane];
        if (relu) {
            v0 = fmaxf(v0, 0.f); v1 = fmaxf(v1, 0.f);
            v2 = fmaxf(v2, 0.f); v3 = fmaxf(v3, 0.f);
        }
        int r0l = 0, r1l = 0, r2l = 0, r3l = 0;
        for (int r = 1; r < gcnt; ++r) {
            int b = bounds[r0 + r];
            r0l += (e >= b); r1l += (e + 1 >= b); r2l += (e + 2 >= b); r3l += (e + 3 >= b);
        }
        unsafeAtomicAdd(&A[((size_t)r0l * N_NODES + s0.y) * HID + lane], v0);
        unsafeAtomicAdd(&A[((size_t)r1l * N_NODES + s1.y) * HID + lane], v1);
        unsafeAtomicAdd(&A[((size_t)r2l * N_NODES + s2.y) * HID + lane], v2);
        unsafeAtomicAdd(&A[((size_t)r3l * N_NODES + s3.y) * HID + lane], v3);
    }
    for (; e < end; ++e) {
        int2 sd = sedge[e];
        float v = feat[(size_t)sd.x * HID + lane];
        if (relu) v = fmaxf(v, 0.f);
        int rl = 0;
        for (int r = 1; r < gcnt; ++r) rl += (e >= bounds[r0 + r]);
        unsafeAtomicAdd(&A[((size_t)rl * N_NODES + sd.y) * HID + lane], v);
    }
}

// K6: layer-1 GEMM sweep. 1 wave/block, 16 nodes/wave, lane = out dim.
// Wc = W1[rel][:,lane] in 64 VGPRs; A rows via uniform scalar loads;
// self-cleans A for the next sweep. Sweep 0 folds in x@root1 + b1.
__global__ __launch_bounds__(64) void gemm1_k(float* __restrict__ A,
                                              const float* __restrict__ W1,
                                              const float* __restrict__ inv,
                                              float* __restrict__ X1,
                                              const float* __restrict__ x,
                                              const float* __restrict__ root1,
                                              const float* __restrict__ b1,
                                              int r0, int gcnt, int first) {
    int lane = threadIdx.x;
    int n0 = blockIdx.x * 16;
    float h[16];
    if (first) {
        float Rc[HID];
#pragma unroll
        for (int k = 0; k < HID; ++k) Rc[k] = root1[k * HID + lane];
        float bias = b1[lane];
#pragma unroll 2
        for (int i = 0; i < 16; ++i) {
            const float* __restrict__ xr = x + (size_t)(n0 + i) * HID;
            float h0 = bias, h1 = 0.f, h2 = 0.f, h3 = 0.f;
#pragma unroll
            for (int k = 0; k < HID; k += 4) {
                h0 = fmaf(xr[k + 0], Rc[k + 0], h0);
                h1 = fmaf(xr[k + 1], Rc[k + 1], h1);
                h2 = fmaf(xr[k + 2], Rc[k + 2], h2);
                h3 = fmaf(xr[k + 3], Rc[k + 3], h3);
            }
            h[i] = (h0 + h1) + (h2 + h3);
        }
    } else {
#pragma unroll
        for (int i = 0; i < 16; ++i) h[i] = X1[(size_t)(n0 + i) * HID + lane];
    }

    for (int rloc = 0; rloc < gcnt; ++rloc) {
        int rel = r0 + rloc;
        float Wc[HID];
#pragma unroll
        for (int k = 0; k < HID; ++k)
            Wc[k] = W1[(size_t)rel * HID * HID + k * HID + lane];
#pragma unroll 2
        for (int i = 0; i < 16; ++i) {
            int n = n0 + i;
            float iv = inv[(size_t)rel * N_NODES + n];
            if (iv != 0.0f) {
                float* __restrict__ ar = A + ((size_t)rloc * N_NODES + n) * HID;
                float h0 = 0.f, h1 = 0.f, h2 = 0.f, h3 = 0.f;
#pragma unroll
                for (int k = 0; k < HID; k += 4) {
                    h0 = fmaf(ar[k + 0], Wc[k + 0], h0);
                    h1 = fmaf(ar[k + 1], Wc[k + 1], h1);
                    h2 = fmaf(ar[k + 2], Wc[k + 2], h2);
                    h3 = fmaf(ar[k + 3], Wc[k + 3], h3);
                }
                h[i] = fmaf(iv, (h0 + h1) + (h2 + h3), h[i]);
                ar[lane] = 0.0f;  // self-clean for next sweep
            }
        }
    }
#pragma unroll
    for (int i = 0; i < 16; ++i) X1[(size_t)(n0 + i) * HID + lane] = h[i];
}

// K7: layer-2 GEMM sweep. 1 wave/block, 16 nodes/wave, lane = (q = k-quarter,
// d = class). Sweep 0 folds in relu(X1)@root2 + b2. Self-cleans A.
__global__ __launch_bounds__(64) void gemm2_k(float* __restrict__ A,
                                              const float* __restrict__ W2,
                                              const float* __restrict__ inv,
                                              float* __restrict__ out,
                                              const float* __restrict__ X1,
                                              const float* __restrict__ root2,
                                              const float* __restrict__ b2,
                                              int r0, int gcnt, int first) {
    int lane = threadIdx.x;
    int d = lane & 15, q = lane >> 4;
    int n0 = blockIdx.x * 16;
    float h[16];
    if (first) {
        float Rc[16];
#pragma unroll
        for (int j = 0; j < 16; ++j) Rc[j] = root2[(q * 16 + j) * NCLS + d];
#pragma unroll 2
        for (int i = 0; i < 16; ++i) {
            const float* __restrict__ xr = X1 + (size_t)(n0 + i) * HID + q * 16;
            float t = 0.f;
#pragma unroll
            for (int j = 0; j < 16; ++j) t = fmaf(fmaxf(xr[j], 0.f), Rc[j], t);
            h[i] = t;
        }
    } else {
#pragma unroll
        for (int i = 0; i < 16; ++i) h[i] = 0.f;
    }

    for (int rloc = 0; rloc < gcnt; ++rloc) {
        int rel = r0 + rloc;
        float Wc[16];
#pragma unroll
        for (int j = 0; j < 16; ++j)
            Wc[j] = W2[(size_t)rel * HID * NCLS + (q * 16 + j) * NCLS + d];
#pragma unroll 2
        for (int i = 0; i < 16; ++i) {
            int n = n0 + i;
            float iv = inv[(size_t)rel * N_NODES + n];
            if (iv != 0.0f) {
                float* __restrict__ ar = A + ((size_t)rloc * N_NODES + n) * HID;
                const float4* __restrict__ ar4 = (const float4*)(ar + q * 16);
                float t = 0.f;
#pragma unroll
                for (int j4 = 0; j4 < 4; ++j4) {
                    float4 v = ar4[j4];
                    t = fmaf(v.x, Wc[j4 * 4 + 0], t);
                    t = fmaf(v.y, Wc[j4 * 4 + 1], t);
                    t = fmaf(v.z, Wc[j4 * 4 + 2], t);
                    t = fmaf(v.w, Wc[j4 * 4 + 3], t);
                }
                h[i] = fmaf(iv, t, h[i]);
                ar[lane] = 0.0f;  // self-clean
            }
        }
    }
#pragma unroll
    for (int i = 0; i < 16; ++i) {
        float t = h[i];
        t += __shfl_xor(t, 16, 64);
        t += __shfl_xor(t, 32, 64);
        if (q == 0) {
            float* op = out + (size_t)(n0 + i) * NCLS + d;
            if (first) *op = t + b2[d];
            else *op += t;
        }
    }
}

extern "C" void kernel_launch(void* const* d_in, const int* in_sizes, int n_in,
                              void* d_out, int out_size, void* d_ws, size_t ws_size,
                              hipStream_t stream) {
    const int* ei    = (const int*)d_in[0];
    const int* et    = (const int*)d_in[1];
    const float* x   = (const float*)d_in[2];
    const float* W1  = (const float*)d_in[3];
    const float* r1  = (const float*)d_in[4];
    const float* b1  = (const float*)d_in[5];
    const float* W2  = (const float*)d_in[6];
    const float* r2  = (const float*)d_in[7];
    const float* b2  = (const float*)d_in[8];
    float* out = (float*)d_out;

    int E = in_sizes[0] / 2;
    const int* srcp = ei;
    const int* dstp = ei + E;
    int NB = (E + 255) / 256;

    // runtime sweep width from ws_size
    size_t per_rel = (size_t)N_NODES * HID * sizeof(float);          // 12.8 MB
    size_t fixed = (size_t)NREL * N_NODES * sizeof(float)            // cnt
                 + (size_t)NREL * NB * sizeof(int) + 32 * sizeof(int) // bh+bounds
                 + (size_t)E * sizeof(int2)                          // sedge
                 + (size_t)N_NODES * HID * sizeof(float);            // X1
    int G = 1;
    if (ws_size > fixed + per_rel)
        G = (int)((ws_size - fixed) / per_rel);
    if (G > NREL) G = NREL;
    if (G < 1) G = 1;

    float* cnt = (float*)d_ws;
    float* A   = cnt + (size_t)NREL * N_NODES;
    int*   bh  = (int*)(A + (size_t)G * N_NODES * HID);
    int*   bounds = bh + (size_t)NREL * NB;
    int2*  sedge  = (int2*)(bounds + 32);
    float* X1  = (float*)(sedge + E);

    // zero cnt + A in one contiguous shot
    hipMemsetAsync(cnt, 0,
                   ((size_t)NREL * N_NODES + (size_t)G * N_NODES * HID) * sizeof(float),
                   stream);

    hist_k<<<NB, 256, 0, stream>>>(dstp, et, cnt, bh, NB, E);
    scan_k<<<1, 1024, 0, stream>>>(bh, bounds, NB);
    scatter_k2<<<NB, 256, 0, stream>>>(srcp, dstp, et, bh, sedge, NB, E);
    inv_k<<<(NREL * N_NODES + 255) / 256, 256, 0, stream>>>(cnt, NREL * N_NODES);

    int gblocks = N_NODES / 16;  // 3125, exact

    for (int r0 = 0; r0 < NREL; r0 += G) {
        int gc = (r0 + G <= NREL) ? G : (NREL - r0);
        agg_k<<<2048, 256, 0, stream>>>(sedge, bounds, x, A, r0, gc, 0);
        gemm1_k<<<gblocks, 64, 0, stream>>>(A, W1, cnt, X1, x, r1, b1, r0, gc, r0 == 0);
    }
    for (int r0 = 0; r0 < NREL; r0 += G) {
        int gc = (r0 + G <= NREL) ? G : (NREL - r0);
        agg_k<<<2048, 256, 0, stream>>>(sedge, bounds, X1, A, r0, gc, 1);
        gemm2_k<<<gblocks, 64, 0, stream>>>(A, W2, cnt, out, X1, r2, b2, r0, gc, r0 == 0);
    }
}

// Round 4
// 605.556 us; speedup vs baseline: 4.9520x; 1.8593x over previous
//
#include <hip/hip_runtime.h>
#include <hip/hip_bf16.h>

#define N_NODES 50000
#define NREL 16
#define HID 64
#define NCLS 16
#define NTILES 3125   // N_NODES / 16

// ---------------------------------------------------------------------------
// ws layout: cnt [16*50000] f32 (3.2MB) | sedge [E] int4 (12.8MB)
//            | H1 [16*50000*64] bf16 (102.4MB) | H2 [16*50000*16] bf16 (25.6MB)
//            | X1 [50000*64] f32 (12.8MB)      total ~157MB
// ---------------------------------------------------------------------------

// K1: per-(rel,dst) edge counts
__global__ __launch_bounds__(256) void cnt_k(const int* __restrict__ dstp,
                                             const int* __restrict__ et,
                                             float* __restrict__ cnt, int E) {
    int i = blockIdx.x * 256 + threadIdx.x;
    if (i < E)
        unsafeAtomicAdd(&cnt[(size_t)et[i] * N_NODES + dstp[i]], 1.0f);
}

// K2: pack per-edge meta {src, dst, inv=1/cnt, rel} (cnt>=1 at every edge)
__global__ __launch_bounds__(256) void pack_k(const int* __restrict__ srcp,
                                              const int* __restrict__ dstp,
                                              const int* __restrict__ et,
                                              const float* __restrict__ cnt,
                                              int4* __restrict__ sedge, int E) {
    int i = blockIdx.x * 256 + threadIdx.x;
    if (i < E) {
        int r = et[i], s = srcp[i], dd = dstp[i];
        float inv = 1.0f / cnt[(size_t)r * N_NODES + dd];
        sedge[i] = make_int4(s, dd, __float_as_int(inv), r);
    }
}

// K3: H1[r] = x @ W1[r] (bf16 out), task 16 = X1 = x @ root1 + b1 (f32).
// One wave per (task, 16-node tile); lane = out dim; W column in 64 VGPRs;
// x rows via wave-uniform scalar loads; 2-node ILP.
__global__ __launch_bounds__(256) void trans1_k(const float* __restrict__ x,
                                                const float* __restrict__ W1,
                                                const float* __restrict__ root1,
                                                const float* __restrict__ b1,
                                                __hip_bfloat16* __restrict__ H1,
                                                float* __restrict__ X1) {
    int wid = __builtin_amdgcn_readfirstlane((blockIdx.x * 256 + threadIdx.x) >> 6);
    int lane = threadIdx.x & 63;
    int task = wid / NTILES;
    if (task > 16) return;
    int tile = wid - task * NTILES;
    int n0 = tile * 16;

    float Wc[HID];
    float bias = 0.0f;
    if (task < 16) {
#pragma unroll
        for (int k = 0; k < HID; ++k)
            Wc[k] = W1[((size_t)task * HID + k) * HID + lane];
    } else {
#pragma unroll
        for (int k = 0; k < HID; ++k)
            Wc[k] = root1[k * HID + lane];
        bias = b1[lane];
    }

    for (int i = 0; i < 16; i += 2) {
        const float* __restrict__ r0 = x + (size_t)(n0 + i) * HID;
        const float* __restrict__ r1 = r0 + HID;
        float a0 = bias, a1 = 0.f, a2 = 0.f, a3 = 0.f;
        float c0 = bias, c1 = 0.f, c2 = 0.f, c3 = 0.f;
#pragma unroll
        for (int k = 0; k < HID; k += 4) {
            a0 = fmaf(r0[k + 0], Wc[k + 0], a0);
            a1 = fmaf(r0[k + 1], Wc[k + 1], a1);
            a2 = fmaf(r0[k + 2], Wc[k + 2], a2);
            a3 = fmaf(r0[k + 3], Wc[k + 3], a3);
            c0 = fmaf(r1[k + 0], Wc[k + 0], c0);
            c1 = fmaf(r1[k + 1], Wc[k + 1], c1);
            c2 = fmaf(r1[k + 2], Wc[k + 2], c2);
            c3 = fmaf(r1[k + 3], Wc[k + 3], c3);
        }
        float h0 = (a0 + a1) + (a2 + a3);
        float h1 = (c0 + c1) + (c2 + c3);
        if (task < 16) {
            H1[((size_t)task * N_NODES + n0 + i) * HID + lane] = __float2bfloat16(h0);
            H1[((size_t)task * N_NODES + n0 + i + 1) * HID + lane] = __float2bfloat16(h1);
        } else {
            X1[(size_t)(n0 + i) * HID + lane] = h0;
            X1[(size_t)(n0 + i + 1) * HID + lane] = h1;
        }
    }
}

// K4: layer-1 edge pass. Wave per edge (lane = dim), 8-edge unroll:
// uniform s_load meta, 128B bf16 gather of H1[rel][src], scaled 256B
// atomic add into X1[dst].
__global__ __launch_bounds__(256) void edge1_k(const int4* __restrict__ sedge,
                                               const __hip_bfloat16* __restrict__ H1,
                                               float* __restrict__ X1, int E) {
    int wid = __builtin_amdgcn_readfirstlane((blockIdx.x * 256 + threadIdx.x) >> 6);
    int lane = threadIdx.x & 63;
    int nw = (gridDim.x * 256) >> 6;

    for (int e0 = wid * 8; e0 < E; e0 += nw * 8) {
        if (e0 + 8 <= E) {
            int4 m[8];
#pragma unroll
            for (int j = 0; j < 8; ++j) m[j] = sedge[e0 + j];
            float v[8];
#pragma unroll
            for (int j = 0; j < 8; ++j)
                v[j] = __bfloat162float(
                    H1[((size_t)m[j].w * N_NODES + m[j].x) * HID + lane]);
#pragma unroll
            for (int j = 0; j < 8; ++j)
                unsafeAtomicAdd(&X1[(size_t)m[j].y * HID + lane],
                                v[j] * __int_as_float(m[j].z));
        } else {
            for (int e = e0; e < E; ++e) {
                int4 m = sedge[e];
                float v = __bfloat162float(
                    H1[((size_t)m.w * N_NODES + m.x) * HID + lane]);
                unsafeAtomicAdd(&X1[(size_t)m.y * HID + lane],
                                v * __int_as_float(m.z));
            }
        }
    }
}

// K5: H2[r] = relu(X1) @ W2[r] (bf16), task 16 = out = relu(X1) @ root2 + b2.
// Wave per (task, 16-node tile); lane = (q = k-quarter, d = class);
// float4 row loads, shfl_xor reduce over quarters.
__global__ __launch_bounds__(256) void trans2_k(const float* __restrict__ X1,
                                                const float* __restrict__ W2,
                                                const float* __restrict__ root2,
                                                const float* __restrict__ b2,
                                                __hip_bfloat16* __restrict__ H2,
                                                float* __restrict__ out) {
    int wid = __builtin_amdgcn_readfirstlane((blockIdx.x * 256 + threadIdx.x) >> 6);
    int lane = threadIdx.x & 63;
    int d = lane & 15, q = lane >> 4;
    int task = wid / NTILES;
    if (task > 16) return;
    int tile = wid - task * NTILES;
    int n0 = tile * 16;

    const float* __restrict__ Wsrc =
        (task < 16) ? (W2 + (size_t)task * HID * NCLS) : root2;
    float Wc[16];
#pragma unroll
    for (int j = 0; j < 16; ++j)
        Wc[j] = Wsrc[(q * 16 + j) * NCLS + d];
    float bias = (task == 16) ? b2[d] : 0.0f;

    for (int i = 0; i < 16; ++i) {
        const float4* __restrict__ xr4 =
            (const float4*)(X1 + (size_t)(n0 + i) * HID);
        float t = 0.f;
#pragma unroll
        for (int j4 = 0; j4 < 4; ++j4) {
            float4 v = xr4[q * 4 + j4];
            t = fmaf(fmaxf(v.x, 0.f), Wc[j4 * 4 + 0], t);
            t = fmaf(fmaxf(v.y, 0.f), Wc[j4 * 4 + 1], t);
            t = fmaf(fmaxf(v.z, 0.f), Wc[j4 * 4 + 2], t);
            t = fmaf(fmaxf(v.w, 0.f), Wc[j4 * 4 + 3], t);
        }
        t += __shfl_xor(t, 16, 64);
        t += __shfl_xor(t, 32, 64);
        if (q == 0) {
            if (task < 16)
                H2[((size_t)task * N_NODES + n0 + i) * NCLS + d] =
                    __float2bfloat16(t);
            else
                out[(size_t)(n0 + i) * NCLS + d] = t + bias;
        }
    }
}

// K6: layer-2 edge pass. 4 edges per wave (16-lane group per edge, lane=class):
// 32B bf16 gather of H2[rel][src], scaled 64B atomic into out[dst].
__global__ __launch_bounds__(256) void edge2_k(const int4* __restrict__ sedge,
                                               const __hip_bfloat16* __restrict__ H2,
                                               float* __restrict__ out, int E) {
    int wid = __builtin_amdgcn_readfirstlane((blockIdx.x * 256 + threadIdx.x) >> 6);
    int lane = threadIdx.x & 63;
    int g = lane >> 4, d = lane & 15;
    int nw = (gridDim.x * 256) >> 6;

    for (int e0 = wid * 4; e0 < E; e0 += nw * 4) {
        int e = e0 + g;
        if (e < E) {
            int4 m = sedge[e];
            float v = __bfloat162float(
                H2[((size_t)m.w * N_NODES + m.x) * NCLS + d]);
            unsafeAtomicAdd(&out[(size_t)m.y * NCLS + d],
                            v * __int_as_float(m.z));
        }
    }
}

extern "C" void kernel_launch(void* const* d_in, const int* in_sizes, int n_in,
                              void* d_out, int out_size, void* d_ws, size_t ws_size,
                              hipStream_t stream) {
    const int* ei    = (const int*)d_in[0];
    const int* et    = (const int*)d_in[1];
    const float* x   = (const float*)d_in[2];
    const float* W1  = (const float*)d_in[3];
    const float* r1  = (const float*)d_in[4];
    const float* b1  = (const float*)d_in[5];
    const float* W2  = (const float*)d_in[6];
    const float* r2  = (const float*)d_in[7];
    const float* b2  = (const float*)d_in[8];
    float* out = (float*)d_out;

    int E = in_sizes[0] / 2;
    const int* srcp = ei;
    const int* dstp = ei + E;

    float* cnt = (float*)d_ws;                                   // 3.2 MB
    int4* sedge = (int4*)(cnt + (size_t)NREL * N_NODES);         // 12.8 MB
    __hip_bfloat16* H1 = (__hip_bfloat16*)(sedge + E);           // 102.4 MB
    __hip_bfloat16* H2 = H1 + (size_t)NREL * N_NODES * HID;      // 25.6 MB
    float* X1 = (float*)(H2 + (size_t)NREL * N_NODES * NCLS);    // 12.8 MB

    hipMemsetAsync(cnt, 0, (size_t)NREL * N_NODES * sizeof(float), stream);

    int eb = (E + 255) / 256;
    cnt_k<<<eb, 256, 0, stream>>>(dstp, et, cnt, E);
    pack_k<<<eb, 256, 0, stream>>>(srcp, dstp, et, cnt, sedge, E);

    // 17 tasks (16 rels + root) x 3125 tiles, 4 waves/block
    int tblocks = (17 * NTILES + 3) / 4;
    trans1_k<<<tblocks, 256, 0, stream>>>(x, W1, r1, b1, H1, X1);
    edge1_k<<<2048, 256, 0, stream>>>(sedge, H1, X1, E);
    trans2_k<<<tblocks, 256, 0, stream>>>(X1, W2, r2, b2, H2, out);
    edge2_k<<<2048, 256, 0, stream>>>(sedge, H2, out, E);
}

// Round 5
// 487.164 us; speedup vs baseline: 6.1554x; 1.2430x over previous
//
#include <hip/hip_runtime.h>
#include <hip/hip_bf16.h>

#define N_NODES 50000
#define NREL 16
#define HID 64
#define NCLS 16
#define NTILES 3125   // N_NODES / 16

typedef __attribute__((ext_vector_type(8))) short bf16x8;
typedef __attribute__((ext_vector_type(4))) float f32x4;

static __device__ __forceinline__ unsigned short f2bf(float f) {
    __hip_bfloat16 h = __float2bfloat16(f);
    return *reinterpret_cast<unsigned short*>(&h);
}
static __device__ __forceinline__ float bf2f(unsigned short u) {
    __hip_bfloat16 h;
    *reinterpret_cast<unsigned short*>(&h) = u;
    return __bfloat162float(h);
}

// ---------------------------------------------------------------------------
// ws layout (bytes):
//   cnt   f32[16*50000]      3.20 MB   (zeroed)
//   dcnt  i32[50000]         0.20 MB   (zeroed, contiguous with cnt)
//   dstart i32[50004]        0.20 MB
//   cursor i32[50000]        0.20 MB
//   sedge int2[E]            6.40 MB   (dst-sorted: {src|(rel<<16), inv bits})
//   xb    bf16[50000*64]     6.40 MB
//   WbT1  bf16[17*64*64]     0.14 MB   (WbT1[t][n][k] = W1/root1[t][k][n])
//   WbT2  bf16[17*16*64]     0.03 MB
//   H1    bf16[16*50000*64]  102.4 MB
//   H2    bf16[16*50000*16]  25.6 MB
//   X1m   bf16[50000*64]     6.40 MB   (trans1 root -> edge1 in-place relu'd)
//   total ~151 MB
// ---------------------------------------------------------------------------

// K1: per-(rel,dst) counts + per-dst degree
__global__ __launch_bounds__(256) void cnt_k(const int* __restrict__ dstp,
                                             const int* __restrict__ et,
                                             float* __restrict__ cnt,
                                             int* __restrict__ dcnt, int E) {
    int i = blockIdx.x * 256 + threadIdx.x;
    if (i < E) {
        int d = dstp[i];
        unsafeAtomicAdd(&cnt[(size_t)et[i] * N_NODES + d], 1.0f);
        atomicAdd(&dcnt[d], 1);
    }
}

// K2: single-block exclusive scan of dcnt[50000] -> dstart[50001], cursor copy
__global__ __launch_bounds__(1024) void scan_k(const int* __restrict__ dcnt,
                                               int* __restrict__ dstart,
                                               int* __restrict__ cursor) {
    __shared__ int ts[1024];
    const int CH = (N_NODES + 1023) / 1024;  // 49
    int t = threadIdx.x;
    int base = t * CH;
    int s = 0;
    for (int i = 0; i < CH; ++i) {
        int idx = base + i;
        if (idx < N_NODES) s += dcnt[idx];
    }
    ts[t] = s;
    __syncthreads();
    int v = s;
    for (int off = 1; off < 1024; off <<= 1) {
        int u = (t >= off) ? ts[t - off] : 0;
        __syncthreads();
        v += u;
        ts[t] = v;
        __syncthreads();
    }
    int run = v - s;  // exclusive prefix at this thread's chunk start
    for (int i = 0; i < CH; ++i) {
        int idx = base + i;
        if (idx < N_NODES) {
            dstart[idx] = run;
            cursor[idx] = run;
            run += dcnt[idx];
        }
    }
    if (t == 1023) dstart[N_NODES] = run;
}

// K3: counting-sort scatter by dst (50k cursors: low contention)
__global__ __launch_bounds__(256) void scat_k(const int* __restrict__ srcp,
                                              const int* __restrict__ dstp,
                                              const int* __restrict__ et,
                                              const float* __restrict__ cnt,
                                              int* __restrict__ cursor,
                                              int2* __restrict__ sedge, int E) {
    int i = blockIdx.x * 256 + threadIdx.x;
    if (i < E) {
        int d = dstp[i], r = et[i], s = srcp[i];
        float inv = 1.0f / cnt[(size_t)r * N_NODES + d];
        int p = atomicAdd(&cursor[d], 1);
        sedge[p] = make_int2(s | (r << 16), __float_as_int(inv));
    }
}

// K4: convert x -> bf16 and build transposed bf16 weights (task 16 = root)
__global__ __launch_bounds__(256) void cvt_k(const float* __restrict__ x,
                                             const float* __restrict__ W1,
                                             const float* __restrict__ root1,
                                             const float* __restrict__ W2,
                                             const float* __restrict__ root2,
                                             ushort* __restrict__ xb,
                                             ushort* __restrict__ WbT1,
                                             ushort* __restrict__ WbT2) {
    int i = blockIdx.x * 256 + threadIdx.x;
    if (i < N_NODES * HID / 4) {
        float4 v = ((const float4*)x)[i];
        ushort4 o;
        o.x = f2bf(v.x); o.y = f2bf(v.y); o.z = f2bf(v.z); o.w = f2bf(v.w);
        ((ushort4*)xb)[i] = o;
    } else if (i < N_NODES * HID / 4 + 17 * HID * HID) {
        int j = i - N_NODES * HID / 4;
        int t = j >> 12;
        int rem = j & 4095;
        int n = rem >> 6, k = rem & 63;
        float v = (t < 16) ? W1[(size_t)t * HID * HID + k * HID + n]
                           : root1[k * HID + n];
        WbT1[j] = f2bf(v);
    } else {
        int j = i - N_NODES * HID / 4 - 17 * HID * HID;
        if (j < 17 * NCLS * HID) {
            int t = j >> 10;
            int rem = j & 1023;
            int n = rem >> 6, k = rem & 63;
            float v = (t < 16) ? W2[(size_t)t * HID * NCLS + k * NCLS + n]
                               : root2[k * NCLS + n];
            WbT2[j] = f2bf(v);
        }
    }
}

// K5: MFMA transform 1. Wave = 16-node tile; A-frags loaded ONCE, reused over
// 17 tasks (16 rels -> H1 bf16, task 16 = x@root1+b1 -> X1m bf16).
__global__ __launch_bounds__(256) void trans1_k(const ushort* __restrict__ xb,
                                                const ushort* __restrict__ WbT1,
                                                const float* __restrict__ b1,
                                                ushort* __restrict__ H1,
                                                ushort* __restrict__ X1m) {
    int wid = (blockIdx.x * 256 + threadIdx.x) >> 6;
    int lane = threadIdx.x & 63;
    if (wid >= NTILES) return;
    int n0 = wid * 16;
    int mr = lane & 15;   // A row / D col
    int kq = lane >> 4;   // k-quad

    const bf16x8* arow = (const bf16x8*)(xb + (size_t)(n0 + mr) * HID + kq * 8);
    bf16x8 a0 = arow[0];   // k in [kq*8, kq*8+8)
    bf16x8 a1 = arow[4];   // +32 elems

    float bias[4];
#pragma unroll
    for (int nt = 0; nt < 4; ++nt) bias[nt] = b1[nt * 16 + mr];

    const ushort* wbase = WbT1 + (size_t)mr * HID + kq * 8;
    for (int t = 0; t < 17; ++t) {
        const ushort* wt = wbase + (size_t)t * HID * HID;
        f32x4 acc[4];
#pragma unroll
        for (int nt = 0; nt < 4; ++nt) {
            bf16x8 b0 = *(const bf16x8*)(wt + nt * 1024);
            bf16x8 bv = *(const bf16x8*)(wt + nt * 1024 + 32);
            f32x4 c = {0.f, 0.f, 0.f, 0.f};
            c = __builtin_amdgcn_mfma_f32_16x16x32_bf16(a0, b0, c, 0, 0, 0);
            c = __builtin_amdgcn_mfma_f32_16x16x32_bf16(a1, bv, c, 0, 0, 0);
            acc[nt] = c;
        }
        if (t < 16) {
            ushort* Ht = H1 + (size_t)t * N_NODES * HID;
#pragma unroll
            for (int nt = 0; nt < 4; ++nt)
#pragma unroll
                for (int r = 0; r < 4; ++r) {
                    int node = n0 + kq * 4 + r;  // D: row = quad*4+reg
                    Ht[(size_t)node * HID + nt * 16 + mr] = f2bf(acc[nt][r]);
                }
        } else {
#pragma unroll
            for (int nt = 0; nt < 4; ++nt)
#pragma unroll
                for (int r = 0; r < 4; ++r) {
                    int node = n0 + kq * 4 + r;
                    X1m[(size_t)node * HID + nt * 16 + mr] =
                        f2bf(acc[nt][r] + bias[nt]);
                }
        }
    }
}

// K6: layer-1 gather. Wave owns dst node: register-accumulate inv*H1[rel][src]
// over its CSR segment (no atomics), fold root + relu, in-place bf16 store.
__global__ __launch_bounds__(256) void edge1_k(const int2* __restrict__ sedge,
                                               const int* __restrict__ dstart,
                                               const ushort* __restrict__ H1,
                                               ushort* __restrict__ X1m) {
    int wid = (blockIdx.x * 256 + threadIdx.x) >> 6;
    int lane = threadIdx.x & 63;
    if (wid >= N_NODES) return;
    int lo = dstart[wid], hi = dstart[wid + 1];
    float acc = bf2f(X1m[(size_t)wid * HID + lane]);
    int e = lo;
    for (; e + 4 <= hi; e += 4) {
        int2 m0 = sedge[e], m1 = sedge[e + 1], m2 = sedge[e + 2], m3 = sedge[e + 3];
        float v0 = bf2f(H1[((size_t)(m0.x >> 16) * N_NODES + (m0.x & 0xFFFF)) * HID + lane]);
        float v1 = bf2f(H1[((size_t)(m1.x >> 16) * N_NODES + (m1.x & 0xFFFF)) * HID + lane]);
        float v2 = bf2f(H1[((size_t)(m2.x >> 16) * N_NODES + (m2.x & 0xFFFF)) * HID + lane]);
        float v3 = bf2f(H1[((size_t)(m3.x >> 16) * N_NODES + (m3.x & 0xFFFF)) * HID + lane]);
        acc = fmaf(__int_as_float(m0.y), v0, acc);
        acc = fmaf(__int_as_float(m1.y), v1, acc);
        acc = fmaf(__int_as_float(m2.y), v2, acc);
        acc = fmaf(__int_as_float(m3.y), v3, acc);
    }
    for (; e < hi; ++e) {
        int2 m = sedge[e];
        float v = bf2f(H1[((size_t)(m.x >> 16) * N_NODES + (m.x & 0xFFFF)) * HID + lane]);
        acc = fmaf(__int_as_float(m.y), v, acc);
    }
    X1m[(size_t)wid * HID + lane] = f2bf(fmaxf(acc, 0.f));  // relu folded
}

// K7: MFMA transform 2. Wave = 16-node tile; A = relu'd X1m (bf16), 17 tasks
// (16 rels -> H2 bf16, task 16 = X1m@root2+b2 -> out f32).
__global__ __launch_bounds__(256) void trans2_k(const ushort* __restrict__ X1m,
                                                const ushort* __restrict__ WbT2,
                                                const float* __restrict__ b2,
                                                ushort* __restrict__ H2,
                                                float* __restrict__ out) {
    int wid = (blockIdx.x * 256 + threadIdx.x) >> 6;
    int lane = threadIdx.x & 63;
    if (wid >= NTILES) return;
    int n0 = wid * 16;
    int mr = lane & 15, kq = lane >> 4;
    const bf16x8* arow = (const bf16x8*)(X1m + (size_t)(n0 + mr) * HID + kq * 8);
    bf16x8 a0 = arow[0];
    bf16x8 a1 = arow[4];
    float bias = b2[mr];
    const ushort* wbase = WbT2 + (size_t)mr * HID + kq * 8;
    for (int t = 0; t < 17; ++t) {
        const ushort* wt = wbase + (size_t)t * NCLS * HID;
        bf16x8 b0 = *(const bf16x8*)(wt);
        bf16x8 bv = *(const bf16x8*)(wt + 32);
        f32x4 c = {0.f, 0.f, 0.f, 0.f};
        c = __builtin_amdgcn_mfma_f32_16x16x32_bf16(a0, b0, c, 0, 0, 0);
        c = __builtin_amdgcn_mfma_f32_16x16x32_bf16(a1, bv, c, 0, 0, 0);
        if (t < 16) {
            ushort* Ht = H2 + (size_t)t * N_NODES * NCLS;
#pragma unroll
            for (int r = 0; r < 4; ++r) {
                int node = n0 + kq * 4 + r;
                Ht[(size_t)node * NCLS + mr] = f2bf(c[r]);
            }
        } else {
#pragma unroll
            for (int r = 0; r < 4; ++r) {
                int node = n0 + kq * 4 + r;
                out[(size_t)node * NCLS + mr] = c[r] + bias;
            }
        }
    }
}

// K8: layer-2 gather. 4 dst per wave (16-lane groups, lane = class); no atomics.
__global__ __launch_bounds__(256) void edge2_k(const int2* __restrict__ sedge,
                                               const int* __restrict__ dstart,
                                               const ushort* __restrict__ H2,
                                               float* __restrict__ out) {
    int wid = (blockIdx.x * 256 + threadIdx.x) >> 6;
    int lane = threadIdx.x & 63;
    int g = lane >> 4, c = lane & 15;
    int d0 = wid * 4 + g;
    if (d0 < N_NODES) {
        int lo = dstart[d0], hi = dstart[d0 + 1];
        float acc = out[(size_t)d0 * NCLS + c];
        int e = lo;
        for (; e + 2 <= hi; e += 2) {
            int2 m0 = sedge[e], m1 = sedge[e + 1];
            float v0 = bf2f(H2[((size_t)(m0.x >> 16) * N_NODES + (m0.x & 0xFFFF)) * NCLS + c]);
            float v1 = bf2f(H2[((size_t)(m1.x >> 16) * N_NODES + (m1.x & 0xFFFF)) * NCLS + c]);
            acc = fmaf(__int_as_float(m0.y), v0, acc);
            acc = fmaf(__int_as_float(m1.y), v1, acc);
        }
        if (e < hi) {
            int2 m = sedge[e];
            float v = bf2f(H2[((size_t)(m.x >> 16) * N_NODES + (m.x & 0xFFFF)) * NCLS + c]);
            acc = fmaf(__int_as_float(m.y), v, acc);
        }
        out[(size_t)d0 * NCLS + c] = acc;
    }
}

extern "C" void kernel_launch(void* const* d_in, const int* in_sizes, int n_in,
                              void* d_out, int out_size, void* d_ws, size_t ws_size,
                              hipStream_t stream) {
    const int* ei    = (const int*)d_in[0];
    const int* et    = (const int*)d_in[1];
    const float* x   = (const float*)d_in[2];
    const float* W1  = (const float*)d_in[3];
    const float* r1  = (const float*)d_in[4];
    const float* b1  = (const float*)d_in[5];
    const float* W2  = (const float*)d_in[6];
    const float* r2  = (const float*)d_in[7];
    const float* b2  = (const float*)d_in[8];
    float* out = (float*)d_out;

    int E = in_sizes[0] / 2;
    const int* srcp = ei;
    const int* dstp = ei + E;

    float* cnt    = (float*)d_ws;
    int*   dcnt   = (int*)(cnt + (size_t)NREL * N_NODES);
    int*   dstart = dcnt + N_NODES;
    int*   cursor = dstart + 50004;
    int2*  sedge  = (int2*)(cursor + N_NODES);
    ushort* xb    = (ushort*)(sedge + E);
    ushort* WbT1  = xb + (size_t)N_NODES * HID;
    ushort* WbT2  = WbT1 + 17 * HID * HID;
    ushort* H1    = WbT2 + 17 * NCLS * HID;
    ushort* H2    = H1 + (size_t)NREL * N_NODES * HID;
    ushort* X1m   = H2 + (size_t)NREL * N_NODES * NCLS;

    // zero cnt + dcnt (contiguous)
    hipMemsetAsync(cnt, 0, ((size_t)NREL * N_NODES + N_NODES) * sizeof(int), stream);

    int eb = (E + 255) / 256;
    int cvtThreads = N_NODES * HID / 4 + 17 * HID * HID + 17 * NCLS * HID;

    cvt_k<<<(cvtThreads + 255) / 256, 256, 0, stream>>>(x, W1, r1, W2, r2, xb, WbT1, WbT2);
    cnt_k<<<eb, 256, 0, stream>>>(dstp, et, cnt, dcnt, E);
    scan_k<<<1, 1024, 0, stream>>>(dcnt, dstart, cursor);
    scat_k<<<eb, 256, 0, stream>>>(srcp, dstp, et, cnt, cursor, sedge, E);

    trans1_k<<<(NTILES + 3) / 4, 256, 0, stream>>>(xb, WbT1, b1, H1, X1m);
    edge1_k<<<(N_NODES + 3) / 4, 256, 0, stream>>>(sedge, dstart, H1, X1m);
    trans2_k<<<(NTILES + 3) / 4, 256, 0, stream>>>(X1m, WbT2, b2, H2, out);
    edge2_k<<<(N_NODES / 4 + 3) / 4, 256, 0, stream>>>(sedge, dstart, H2, out);
}

// Round 6
// 362.142 us; speedup vs baseline: 8.2804x; 1.3452x over previous
//
#include <hip/hip_runtime.h>
#include <hip/hip_bf16.h>

#define N_NODES 50000
#define NREL 16
#define HID 64
#define NCLS 16
#define NTILES 3125   // N_NODES / 16
#define SB 512        // scan elems per block
#define NSB ((N_NODES + SB - 1) / SB)   // 98

typedef __attribute__((ext_vector_type(8))) short bf16x8;
typedef __attribute__((ext_vector_type(4))) float f32x4;

static __device__ __forceinline__ unsigned short f2bf(float f) {
    __hip_bfloat16 h = __float2bfloat16(f);
    return *reinterpret_cast<unsigned short*>(&h);
}
static __device__ __forceinline__ float bf2f(unsigned short u) {
    __hip_bfloat16 h;
    *reinterpret_cast<unsigned short*>(&h) = u;
    return __bfloat162float(h);
}

// ---------------------------------------------------------------------------
// ws layout:
//   cnt   f32[16*50000] | dcnt i32[50000] | dstart i32[50004]
//   | cursor i32[50000] | bsum i32[100] | sedge int2[E]
//   | xb bf16[50000*64] | WbT1 bf16[17*64*64] | WbT2 bf16[17*16*64]
//   | H1 bf16[16*50000*64] | H2 bf16[16*50000*16] | X1m bf16[50000*64]
// ---------------------------------------------------------------------------

// K1: per-(rel,dst) counts + per-dst degree
__global__ __launch_bounds__(256) void cnt_k(const int* __restrict__ dstp,
                                             const int* __restrict__ et,
                                             float* __restrict__ cnt,
                                             int* __restrict__ dcnt, int E) {
    int i = blockIdx.x * 256 + threadIdx.x;
    if (i < E) {
        int d = dstp[i];
        unsafeAtomicAdd(&cnt[(size_t)et[i] * N_NODES + d], 1.0f);
        atomicAdd(&dcnt[d], 1);
    }
}

// K2a: per-block sums of dcnt (512 elems / block)
__global__ __launch_bounds__(256) void scan1_k(const int* __restrict__ dcnt,
                                               int* __restrict__ bsum) {
    int b = blockIdx.x, t = threadIdx.x;
    int i0 = b * SB + t * 2;
    int s = 0;
    if (i0 < N_NODES) s += dcnt[i0];
    if (i0 + 1 < N_NODES) s += dcnt[i0 + 1];
#pragma unroll
    for (int off = 1; off < 64; off <<= 1) s += __shfl_xor(s, off, 64);
    __shared__ int ws[4];
    if ((t & 63) == 0) ws[t >> 6] = s;
    __syncthreads();
    if (t == 0) bsum[b] = ws[0] + ws[1] + ws[2] + ws[3];
}

// K2b: exclusive scan of bsum[NSB] (one 128-thread block); dstart[N] = E
__global__ __launch_bounds__(128) void scan2_k(int* __restrict__ bsum,
                                               int* __restrict__ dstart, int E) {
    __shared__ int ts[128];
    int t = threadIdx.x;
    int v = (t < NSB) ? bsum[t] : 0;
    ts[t] = v;
    __syncthreads();
    int acc = v;
    for (int off = 1; off < 128; off <<= 1) {
        int u = (t >= off) ? ts[t - off] : 0;
        __syncthreads();
        acc += u;
        ts[t] = acc;
        __syncthreads();
    }
    if (t < NSB) bsum[t] = acc - v;  // exclusive base per block
    if (t == 0) dstart[N_NODES] = E;
}

// K2c: per-block exclusive scan + global base -> dstart, cursor
__global__ __launch_bounds__(256) void scan3_k(const int* __restrict__ dcnt,
                                               const int* __restrict__ bsum,
                                               int* __restrict__ dstart,
                                               int* __restrict__ cursor) {
    int b = blockIdx.x, t = threadIdx.x;
    int i0 = b * SB + t * 2;
    int a0 = (i0 < N_NODES) ? dcnt[i0] : 0;
    int a1 = (i0 + 1 < N_NODES) ? dcnt[i0 + 1] : 0;
    int s = a0 + a1;
    __shared__ int ts[256];
    ts[t] = s;
    __syncthreads();
    int acc = s;
    for (int off = 1; off < 256; off <<= 1) {
        int u = (t >= off) ? ts[t - off] : 0;
        __syncthreads();
        acc += u;
        ts[t] = acc;
        __syncthreads();
    }
    int base = bsum[b] + (acc - s);  // exclusive prefix at i0
    if (i0 < N_NODES) { dstart[i0] = base; cursor[i0] = base; }
    if (i0 + 1 < N_NODES) { dstart[i0 + 1] = base + a0; cursor[i0 + 1] = base + a0; }
}

// K3: counting-sort scatter by dst (50k cursors: low contention)
__global__ __launch_bounds__(256) void scat_k(const int* __restrict__ srcp,
                                              const int* __restrict__ dstp,
                                              const int* __restrict__ et,
                                              const float* __restrict__ cnt,
                                              int* __restrict__ cursor,
                                              int2* __restrict__ sedge, int E) {
    int i = blockIdx.x * 256 + threadIdx.x;
    if (i < E) {
        int d = dstp[i], r = et[i], s = srcp[i];
        float inv = 1.0f / cnt[(size_t)r * N_NODES + d];
        int p = atomicAdd(&cursor[d], 1);
        sedge[p] = make_int2(s | (r << 16), __float_as_int(inv));
    }
}

// K4: convert x -> bf16 and build transposed bf16 weights (task 16 = root)
__global__ __launch_bounds__(256) void cvt_k(const float* __restrict__ x,
                                             const float* __restrict__ W1,
                                             const float* __restrict__ root1,
                                             const float* __restrict__ W2,
                                             const float* __restrict__ root2,
                                             ushort* __restrict__ xb,
                                             ushort* __restrict__ WbT1,
                                             ushort* __restrict__ WbT2) {
    int i = blockIdx.x * 256 + threadIdx.x;
    if (i < N_NODES * HID / 4) {
        float4 v = ((const float4*)x)[i];
        ushort4 o;
        o.x = f2bf(v.x); o.y = f2bf(v.y); o.z = f2bf(v.z); o.w = f2bf(v.w);
        ((ushort4*)xb)[i] = o;
    } else if (i < N_NODES * HID / 4 + 17 * HID * HID) {
        int j = i - N_NODES * HID / 4;
        int t = j >> 12;
        int rem = j & 4095;
        int n = rem >> 6, k = rem & 63;
        float v = (t < 16) ? W1[(size_t)t * HID * HID + k * HID + n]
                           : root1[k * HID + n];
        WbT1[j] = f2bf(v);
    } else {
        int j = i - N_NODES * HID / 4 - 17 * HID * HID;
        if (j < 17 * NCLS * HID) {
            int t = j >> 10;
            int rem = j & 1023;
            int n = rem >> 6, k = rem & 63;
            float v = (t < 16) ? W2[(size_t)t * HID * NCLS + k * NCLS + n]
                               : root2[k * NCLS + n];
            WbT2[j] = f2bf(v);
        }
    }
}

// K5: MFMA transform 1. Wave = 16-node tile; A-frags loaded ONCE, reused over
// 17 tasks (16 rels -> H1 bf16, task 16 = x@root1+b1 -> X1m bf16).
__global__ __launch_bounds__(256) void trans1_k(const ushort* __restrict__ xb,
                                                const ushort* __restrict__ WbT1,
                                                const float* __restrict__ b1,
                                                ushort* __restrict__ H1,
                                                ushort* __restrict__ X1m) {
    int wid = (blockIdx.x * 256 + threadIdx.x) >> 6;
    int lane = threadIdx.x & 63;
    if (wid >= NTILES) return;
    int n0 = wid * 16;
    int mr = lane & 15;   // A row / D col
    int kq = lane >> 4;   // k-quad

    const bf16x8* arow = (const bf16x8*)(xb + (size_t)(n0 + mr) * HID + kq * 8);
    bf16x8 a0 = arow[0];   // k in [kq*8, kq*8+8)
    bf16x8 a1 = arow[4];   // +32 elems

    float bias[4];
#pragma unroll
    for (int nt = 0; nt < 4; ++nt) bias[nt] = b1[nt * 16 + mr];

    const ushort* wbase = WbT1 + (size_t)mr * HID + kq * 8;
    for (int t = 0; t < 17; ++t) {
        const ushort* wt = wbase + (size_t)t * HID * HID;
        f32x4 acc[4];
#pragma unroll
        for (int nt = 0; nt < 4; ++nt) {
            bf16x8 b0 = *(const bf16x8*)(wt + nt * 1024);
            bf16x8 bv = *(const bf16x8*)(wt + nt * 1024 + 32);
            f32x4 c = {0.f, 0.f, 0.f, 0.f};
            c = __builtin_amdgcn_mfma_f32_16x16x32_bf16(a0, b0, c, 0, 0, 0);
            c = __builtin_amdgcn_mfma_f32_16x16x32_bf16(a1, bv, c, 0, 0, 0);
            acc[nt] = c;
        }
        if (t < 16) {
            ushort* Ht = H1 + (size_t)t * N_NODES * HID;
#pragma unroll
            for (int nt = 0; nt < 4; ++nt)
#pragma unroll
                for (int r = 0; r < 4; ++r) {
                    int node = n0 + kq * 4 + r;  // D: row = quad*4+reg
                    Ht[(size_t)node * HID + nt * 16 + mr] = f2bf(acc[nt][r]);
                }
        } else {
#pragma unroll
            for (int nt = 0; nt < 4; ++nt)
#pragma unroll
                for (int r = 0; r < 4; ++r) {
                    int node = n0 + kq * 4 + r;
                    X1m[(size_t)node * HID + nt * 16 + mr] =
                        f2bf(acc[nt][r] + bias[nt]);
                }
        }
    }
}

// K6: layer-1 gather. Wave owns dst node: register-accumulate inv*H1[rel][src]
// over its CSR segment (no atomics), fold root + relu, in-place bf16 store.
__global__ __launch_bounds__(256) void edge1_k(const int2* __restrict__ sedge,
                                               const int* __restrict__ dstart,
                                               const ushort* __restrict__ H1,
                                               ushort* __restrict__ X1m) {
    int wid = (blockIdx.x * 256 + threadIdx.x) >> 6;
    int lane = threadIdx.x & 63;
    if (wid >= N_NODES) return;
    int lo = dstart[wid], hi = dstart[wid + 1];
    float acc = bf2f(X1m[(size_t)wid * HID + lane]);
    int e = lo;
    for (; e + 4 <= hi; e += 4) {
        int2 m0 = sedge[e], m1 = sedge[e + 1], m2 = sedge[e + 2], m3 = sedge[e + 3];
        float v0 = bf2f(H1[((size_t)(m0.x >> 16) * N_NODES + (m0.x & 0xFFFF)) * HID + lane]);
        float v1 = bf2f(H1[((size_t)(m1.x >> 16) * N_NODES + (m1.x & 0xFFFF)) * HID + lane]);
        float v2 = bf2f(H1[((size_t)(m2.x >> 16) * N_NODES + (m2.x & 0xFFFF)) * HID + lane]);
        float v3 = bf2f(H1[((size_t)(m3.x >> 16) * N_NODES + (m3.x & 0xFFFF)) * HID + lane]);
        acc = fmaf(__int_as_float(m0.y), v0, acc);
        acc = fmaf(__int_as_float(m1.y), v1, acc);
        acc = fmaf(__int_as_float(m2.y), v2, acc);
        acc = fmaf(__int_as_float(m3.y), v3, acc);
    }
    for (; e < hi; ++e) {
        int2 m = sedge[e];
        float v = bf2f(H1[((size_t)(m.x >> 16) * N_NODES + (m.x & 0xFFFF)) * HID + lane]);
        acc = fmaf(__int_as_float(m.y), v, acc);
    }
    X1m[(size_t)wid * HID + lane] = f2bf(fmaxf(acc, 0.f));  // relu folded
}

// K7: MFMA transform 2. Wave = 16-node tile; A = relu'd X1m (bf16), 17 tasks
// (16 rels -> H2 bf16, task 16 = X1m@root2+b2 -> out f32).
__global__ __launch_bounds__(256) void trans2_k(const ushort* __restrict__ X1m,
                                                const ushort* __restrict__ WbT2,
                                                const float* __restrict__ b2,
                                                ushort* __restrict__ H2,
                                                float* __restrict__ out) {
    int wid = (blockIdx.x * 256 + threadIdx.x) >> 6;
    int lane = threadIdx.x & 63;
    if (wid >= NTILES) return;
    int n0 = wid * 16;
    int mr = lane & 15, kq = lane >> 4;
    const bf16x8* arow = (const bf16x8*)(X1m + (size_t)(n0 + mr) * HID + kq * 8);
    bf16x8 a0 = arow[0];
    bf16x8 a1 = arow[4];
    float bias = b2[mr];
    const ushort* wbase = WbT2 + (size_t)mr * HID + kq * 8;
    for (int t = 0; t < 17; ++t) {
        const ushort* wt = wbase + (size_t)t * NCLS * HID;
        bf16x8 b0 = *(const bf16x8*)(wt);
        bf16x8 bv = *(const bf16x8*)(wt + 32);
        f32x4 c = {0.f, 0.f, 0.f, 0.f};
        c = __builtin_amdgcn_mfma_f32_16x16x32_bf16(a0, b0, c, 0, 0, 0);
        c = __builtin_amdgcn_mfma_f32_16x16x32_bf16(a1, bv, c, 0, 0, 0);
        if (t < 16) {
            ushort* Ht = H2 + (size_t)t * N_NODES * NCLS;
#pragma unroll
            for (int r = 0; r < 4; ++r) {
                int node = n0 + kq * 4 + r;
                Ht[(size_t)node * NCLS + mr] = f2bf(c[r]);
            }
        } else {
#pragma unroll
            for (int r = 0; r < 4; ++r) {
                int node = n0 + kq * 4 + r;
                out[(size_t)node * NCLS + mr] = c[r] + bias;
            }
        }
    }
}

// K8: layer-2 gather. 4 dst per wave (16-lane groups, lane = class); no atomics.
__global__ __launch_bounds__(256) void edge2_k(const int2* __restrict__ sedge,
                                               const int* __restrict__ dstart,
                                               const ushort* __restrict__ H2,
                                               float* __restrict__ out) {
    int wid = (blockIdx.x * 256 + threadIdx.x) >> 6;
    int lane = threadIdx.x & 63;
    int g = lane >> 4, c = lane & 15;
    int d0 = wid * 4 + g;
    if (d0 < N_NODES) {
        int lo = dstart[d0], hi = dstart[d0 + 1];
        float acc = out[(size_t)d0 * NCLS + c];
        int e = lo;
        for (; e + 2 <= hi; e += 2) {
            int2 m0 = sedge[e], m1 = sedge[e + 1];
            float v0 = bf2f(H2[((size_t)(m0.x >> 16) * N_NODES + (m0.x & 0xFFFF)) * NCLS + c]);
            float v1 = bf2f(H2[((size_t)(m1.x >> 16) * N_NODES + (m1.x & 0xFFFF)) * NCLS + c]);
            acc = fmaf(__int_as_float(m0.y), v0, acc);
            acc = fmaf(__int_as_float(m1.y), v1, acc);
        }
        if (e < hi) {
            int2 m = sedge[e];
            float v = bf2f(H2[((size_t)(m.x >> 16) * N_NODES + (m.x & 0xFFFF)) * NCLS + c]);
            acc = fmaf(__int_as_float(m.y), v, acc);
        }
        out[(size_t)d0 * NCLS + c] = acc;
    }
}

extern "C" void kernel_launch(void* const* d_in, const int* in_sizes, int n_in,
                              void* d_out, int out_size, void* d_ws, size_t ws_size,
                              hipStream_t stream) {
    const int* ei    = (const int*)d_in[0];
    const int* et    = (const int*)d_in[1];
    const float* x   = (const float*)d_in[2];
    const float* W1  = (const float*)d_in[3];
    const float* r1  = (const float*)d_in[4];
    const float* b1  = (const float*)d_in[5];
    const float* W2  = (const float*)d_in[6];
    const float* r2  = (const float*)d_in[7];
    const float* b2  = (const float*)d_in[8];
    float* out = (float*)d_out;

    int E = in_sizes[0] / 2;
    const int* srcp = ei;
    const int* dstp = ei + E;

    float* cnt    = (float*)d_ws;
    int*   dcnt   = (int*)(cnt + (size_t)NREL * N_NODES);
    int*   dstart = dcnt + N_NODES;
    int*   cursor = dstart + 50004;
    int*   bsum   = cursor + N_NODES;                 // 100 ints (98 used)
    int2*  sedge  = (int2*)(bsum + 100);
    ushort* xb    = (ushort*)(sedge + E);
    ushort* WbT1  = xb + (size_t)N_NODES * HID;
    ushort* WbT2  = WbT1 + 17 * HID * HID;
    ushort* H1    = WbT2 + 17 * NCLS * HID;
    ushort* H2    = H1 + (size_t)NREL * N_NODES * HID;
    ushort* X1m   = H2 + (size_t)NREL * N_NODES * NCLS;

    // zero cnt + dcnt (contiguous)
    hipMemsetAsync(cnt, 0, ((size_t)NREL * N_NODES + N_NODES) * sizeof(int), stream);

    int eb = (E + 255) / 256;
    int cvtThreads = N_NODES * HID / 4 + 17 * HID * HID + 17 * NCLS * HID;

    cvt_k<<<(cvtThreads + 255) / 256, 256, 0, stream>>>(x, W1, r1, W2, r2, xb, WbT1, WbT2);
    cnt_k<<<eb, 256, 0, stream>>>(dstp, et, cnt, dcnt, E);
    scan1_k<<<NSB, 256, 0, stream>>>(dcnt, bsum);
    scan2_k<<<1, 128, 0, stream>>>(bsum, dstart, E);
    scan3_k<<<NSB, 256, 0, stream>>>(dcnt, bsum, dstart, cursor);
    scat_k<<<eb, 256, 0, stream>>>(srcp, dstp, et, cnt, cursor, sedge, E);

    trans1_k<<<(NTILES + 3) / 4, 256, 0, stream>>>(xb, WbT1, b1, H1, X1m);
    edge1_k<<<(N_NODES + 3) / 4, 256, 0, stream>>>(sedge, dstart, H1, X1m);
    trans2_k<<<(NTILES + 3) / 4, 256, 0, stream>>>(X1m, WbT2, b2, H2, out);
    edge2_k<<<(N_NODES / 4 + 3) / 4, 256, 0, stream>>>(sedge, dstart, H2, out);
}

// Round 7
// 349.976 us; speedup vs baseline: 8.5683x; 1.0348x over previous
//
#include <hip/hip_runtime.h>
#include <hip/hip_bf16.h>

#define N_NODES 50000
#define NREL 16
#define HID 64
#define NCLS 16
#define NTILES 3125   // N_NODES / 16
#define SB 512        // scan elems per block
#define NSB ((N_NODES + SB - 1) / SB)   // 98

typedef __attribute__((ext_vector_type(8))) short bf16x8;
typedef __attribute__((ext_vector_type(4))) float f32x4;

static __device__ __forceinline__ unsigned short f2bf(float f) {
    __hip_bfloat16 h = __float2bfloat16(f);
    return *reinterpret_cast<unsigned short*>(&h);
}
static __device__ __forceinline__ float bf2f(unsigned short u) {
    __hip_bfloat16 h;
    *reinterpret_cast<unsigned short*>(&h) = u;
    return __bfloat162float(h);
}

// ---------------------------------------------------------------------------
// ws layout:
//   cnt f32[16*50000] | dcnt i32[50000] | dstart i32[50004] | cursor i32[50000]
//   | bsum i32[100] | sedge int2[E] | xb bf16[50000*64]
//   | WbT1 bf16[17*64*64] | WbT2 bf16[17*16*64]
//   | H1 bf16[16*50000*64]  SWIZZLED: row elem j holds col (j&3)*16+(j>>2)
//   | H2 bf16[16*50000*16] | X1m bf16[50000*64] (standard layout)
// ---------------------------------------------------------------------------

// K1: per-(rel,dst) counts + per-dst degree
__global__ __launch_bounds__(256) void cnt_k(const int* __restrict__ dstp,
                                             const int* __restrict__ et,
                                             float* __restrict__ cnt,
                                             int* __restrict__ dcnt, int E) {
    int i = blockIdx.x * 256 + threadIdx.x;
    if (i < E) {
        int d = dstp[i];
        unsafeAtomicAdd(&cnt[(size_t)et[i] * N_NODES + d], 1.0f);
        atomicAdd(&dcnt[d], 1);
    }
}

// K2a: per-block sums of dcnt
__global__ __launch_bounds__(256) void scan1_k(const int* __restrict__ dcnt,
                                               int* __restrict__ bsum) {
    int b = blockIdx.x, t = threadIdx.x;
    int i0 = b * SB + t * 2;
    int s = 0;
    if (i0 < N_NODES) s += dcnt[i0];
    if (i0 + 1 < N_NODES) s += dcnt[i0 + 1];
#pragma unroll
    for (int off = 1; off < 64; off <<= 1) s += __shfl_xor(s, off, 64);
    __shared__ int ws[4];
    if ((t & 63) == 0) ws[t >> 6] = s;
    __syncthreads();
    if (t == 0) bsum[b] = ws[0] + ws[1] + ws[2] + ws[3];
}

// K2b: exclusive scan of bsum[NSB]
__global__ __launch_bounds__(128) void scan2_k(int* __restrict__ bsum,
                                               int* __restrict__ dstart, int E) {
    __shared__ int ts[128];
    int t = threadIdx.x;
    int v = (t < NSB) ? bsum[t] : 0;
    ts[t] = v;
    __syncthreads();
    int acc = v;
    for (int off = 1; off < 128; off <<= 1) {
        int u = (t >= off) ? ts[t - off] : 0;
        __syncthreads();
        acc += u;
        ts[t] = acc;
        __syncthreads();
    }
    if (t < NSB) bsum[t] = acc - v;
    if (t == 0) dstart[N_NODES] = E;
}

// K2c: per-block exclusive scan + global base -> dstart, cursor
__global__ __launch_bounds__(256) void scan3_k(const int* __restrict__ dcnt,
                                               const int* __restrict__ bsum,
                                               int* __restrict__ dstart,
                                               int* __restrict__ cursor) {
    int b = blockIdx.x, t = threadIdx.x;
    int i0 = b * SB + t * 2;
    int a0 = (i0 < N_NODES) ? dcnt[i0] : 0;
    int a1 = (i0 + 1 < N_NODES) ? dcnt[i0 + 1] : 0;
    int s = a0 + a1;
    __shared__ int ts[256];
    ts[t] = s;
    __syncthreads();
    int acc = s;
    for (int off = 1; off < 256; off <<= 1) {
        int u = (t >= off) ? ts[t - off] : 0;
        __syncthreads();
        acc += u;
        ts[t] = acc;
        __syncthreads();
    }
    int base = bsum[b] + (acc - s);
    if (i0 < N_NODES) { dstart[i0] = base; cursor[i0] = base; }
    if (i0 + 1 < N_NODES) { dstart[i0 + 1] = base + a0; cursor[i0 + 1] = base + a0; }
}

// K3: counting-sort scatter by dst
__global__ __launch_bounds__(256) void scat_k(const int* __restrict__ srcp,
                                              const int* __restrict__ dstp,
                                              const int* __restrict__ et,
                                              const float* __restrict__ cnt,
                                              int* __restrict__ cursor,
                                              int2* __restrict__ sedge, int E) {
    int i = blockIdx.x * 256 + threadIdx.x;
    if (i < E) {
        int d = dstp[i], r = et[i], s = srcp[i];
        float inv = 1.0f / cnt[(size_t)r * N_NODES + d];
        int p = atomicAdd(&cursor[d], 1);
        sedge[p] = make_int2(s | (r << 16), __float_as_int(inv));
    }
}

// K4: convert x -> bf16, build transposed bf16 weights (task 16 = root)
__global__ __launch_bounds__(256) void cvt_k(const float* __restrict__ x,
                                             const float* __restrict__ W1,
                                             const float* __restrict__ root1,
                                             const float* __restrict__ W2,
                                             const float* __restrict__ root2,
                                             ushort* __restrict__ xb,
                                             ushort* __restrict__ WbT1,
                                             ushort* __restrict__ WbT2) {
    int i = blockIdx.x * 256 + threadIdx.x;
    if (i < N_NODES * HID / 4) {
        float4 v = ((const float4*)x)[i];
        ushort4 o;
        o.x = f2bf(v.x); o.y = f2bf(v.y); o.z = f2bf(v.z); o.w = f2bf(v.w);
        ((ushort4*)xb)[i] = o;
    } else if (i < N_NODES * HID / 4 + 17 * HID * HID) {
        int j = i - N_NODES * HID / 4;
        int t = j >> 12;
        int rem = j & 4095;
        int n = rem >> 6, k = rem & 63;
        float v = (t < 16) ? W1[(size_t)t * HID * HID + k * HID + n]
                           : root1[k * HID + n];
        WbT1[j] = f2bf(v);
    } else {
        int j = i - N_NODES * HID / 4 - 17 * HID * HID;
        if (j < 17 * NCLS * HID) {
            int t = j >> 10;
            int rem = j & 1023;
            int n = rem >> 6, k = rem & 63;
            float v = (t < 16) ? W2[(size_t)t * HID * NCLS + k * NCLS + n]
                               : root2[k * NCLS + n];
            WbT2[j] = f2bf(v);
        }
    }
}

// K5: MFMA transform 1, task-split into 3 groups (6+6+5 incl root).
// H1 stores SWIZZLED as ushort4 (8B/lane): Ht[node*64 + mr*4 + nt].
__global__ __launch_bounds__(256) void trans1_k(const ushort* __restrict__ xb,
                                                const ushort* __restrict__ WbT1,
                                                const float* __restrict__ b1,
                                                ushort* __restrict__ H1,
                                                ushort* __restrict__ X1m) {
    int wid = (blockIdx.x * 256 + threadIdx.x) >> 6;
    int lane = threadIdx.x & 63;
    int grp = wid / NTILES;
    if (grp >= 3) return;
    int tile = wid - grp * NTILES;
    int n0 = tile * 16;
    int mr = lane & 15;   // A row / D col
    int kq = lane >> 4;   // k-quad

    const bf16x8* arow = (const bf16x8*)(xb + (size_t)(n0 + mr) * HID + kq * 8);
    bf16x8 a0 = arow[0];
    bf16x8 a1 = arow[4];

    int t0 = grp * 6;
    int t1 = (grp == 2) ? 17 : (t0 + 6);

    const ushort* wbase = WbT1 + (size_t)mr * HID + kq * 8;
    for (int t = t0; t < t1; ++t) {
        const ushort* wt = wbase + (size_t)t * HID * HID;
        f32x4 acc[4];
#pragma unroll
        for (int nt = 0; nt < 4; ++nt) {
            bf16x8 b0 = *(const bf16x8*)(wt + nt * 1024);
            bf16x8 bv = *(const bf16x8*)(wt + nt * 1024 + 32);
            f32x4 c = {0.f, 0.f, 0.f, 0.f};
            c = __builtin_amdgcn_mfma_f32_16x16x32_bf16(a0, b0, c, 0, 0, 0);
            c = __builtin_amdgcn_mfma_f32_16x16x32_bf16(a1, bv, c, 0, 0, 0);
            acc[nt] = c;
        }
        if (t < 16) {
            ushort* Ht = H1 + (size_t)t * N_NODES * HID;
#pragma unroll
            for (int r = 0; r < 4; ++r) {
                int node = n0 + kq * 4 + r;  // D row = quad*4+reg
                ushort4 o;
                o.x = f2bf(acc[0][r]); o.y = f2bf(acc[1][r]);
                o.z = f2bf(acc[2][r]); o.w = f2bf(acc[3][r]);
                *(ushort4*)(Ht + (size_t)node * HID + mr * 4) = o;
            }
        } else {
            // root task: standard layout (trans2 A-frags need it) + bias
#pragma unroll
            for (int nt = 0; nt < 4; ++nt) {
                float bias = b1[nt * 16 + mr];
#pragma unroll
                for (int r = 0; r < 4; ++r) {
                    int node = n0 + kq * 4 + r;
                    X1m[(size_t)node * HID + nt * 16 + mr] =
                        f2bf(acc[nt][r] + bias);
                }
            }
        }
    }
}

// K6: layer-1 gather. Wave owns dst node; lane j covers col (j&3)*16+(j>>2)
// (H1 swizzle). Register-accumulate inv*H1[rel][src], fold root+relu,
// store X1m (standard layout via permuted lane col).
__global__ __launch_bounds__(256) void edge1_k(const int2* __restrict__ sedge,
                                               const int* __restrict__ dstart,
                                               const ushort* __restrict__ H1,
                                               ushort* __restrict__ X1m) {
    int wid = (blockIdx.x * 256 + threadIdx.x) >> 6;
    int lane = threadIdx.x & 63;
    if (wid >= N_NODES) return;
    int col = (lane & 3) * 16 + (lane >> 2);  // logical col of swizzle slot `lane`
    int lo = dstart[wid], hi = dstart[wid + 1];
    float acc = bf2f(X1m[(size_t)wid * HID + col]);
    int e = lo;
    for (; e + 4 <= hi; e += 4) {
        int2 m0 = sedge[e], m1 = sedge[e + 1], m2 = sedge[e + 2], m3 = sedge[e + 3];
        float v0 = bf2f(H1[((size_t)(m0.x >> 16) * N_NODES + (m0.x & 0xFFFF)) * HID + lane]);
        float v1 = bf2f(H1[((size_t)(m1.x >> 16) * N_NODES + (m1.x & 0xFFFF)) * HID + lane]);
        float v2 = bf2f(H1[((size_t)(m2.x >> 16) * N_NODES + (m2.x & 0xFFFF)) * HID + lane]);
        float v3 = bf2f(H1[((size_t)(m3.x >> 16) * N_NODES + (m3.x & 0xFFFF)) * HID + lane]);
        acc = fmaf(__int_as_float(m0.y), v0, acc);
        acc = fmaf(__int_as_float(m1.y), v1, acc);
        acc = fmaf(__int_as_float(m2.y), v2, acc);
        acc = fmaf(__int_as_float(m3.y), v3, acc);
    }
    for (; e < hi; ++e) {
        int2 m = sedge[e];
        float v = bf2f(H1[((size_t)(m.x >> 16) * N_NODES + (m.x & 0xFFFF)) * HID + lane]);
        acc = fmaf(__int_as_float(m.y), v, acc);
    }
    X1m[(size_t)wid * HID + col] = f2bf(fmaxf(acc, 0.f));  // relu folded
}

// K7: MFMA transform 2, task-split into 3 groups. A = relu'd X1m (standard).
__global__ __launch_bounds__(256) void trans2_k(const ushort* __restrict__ X1m,
                                                const ushort* __restrict__ WbT2,
                                                const float* __restrict__ b2,
                                                ushort* __restrict__ H2,
                                                float* __restrict__ out) {
    int wid = (blockIdx.x * 256 + threadIdx.x) >> 6;
    int lane = threadIdx.x & 63;
    int grp = wid / NTILES;
    if (grp >= 3) return;
    int tile = wid - grp * NTILES;
    int n0 = tile * 16;
    int mr = lane & 15, kq = lane >> 4;
    const bf16x8* arow = (const bf16x8*)(X1m + (size_t)(n0 + mr) * HID + kq * 8);
    bf16x8 a0 = arow[0];
    bf16x8 a1 = arow[4];
    int t0 = grp * 6;
    int t1 = (grp == 2) ? 17 : (t0 + 6);
    const ushort* wbase = WbT2 + (size_t)mr * HID + kq * 8;
    for (int t = t0; t < t1; ++t) {
        const ushort* wt = wbase + (size_t)t * NCLS * HID;
        bf16x8 b0 = *(const bf16x8*)(wt);
        bf16x8 bv = *(const bf16x8*)(wt + 32);
        f32x4 c = {0.f, 0.f, 0.f, 0.f};
        c = __builtin_amdgcn_mfma_f32_16x16x32_bf16(a0, b0, c, 0, 0, 0);
        c = __builtin_amdgcn_mfma_f32_16x16x32_bf16(a1, bv, c, 0, 0, 0);
        if (t < 16) {
            ushort* Ht = H2 + (size_t)t * N_NODES * NCLS;
#pragma unroll
            for (int r = 0; r < 4; ++r) {
                int node = n0 + kq * 4 + r;
                Ht[(size_t)node * NCLS + mr] = f2bf(c[r]);
            }
        } else {
            float bias = b2[mr];
#pragma unroll
            for (int r = 0; r < 4; ++r) {
                int node = n0 + kq * 4 + r;
                out[(size_t)node * NCLS + mr] = c[r] + bias;
            }
        }
    }
}

// K8: layer-2 gather. 4 dst per wave (16-lane groups, lane = class).
__global__ __launch_bounds__(256) void edge2_k(const int2* __restrict__ sedge,
                                               const int* __restrict__ dstart,
                                               const ushort* __restrict__ H2,
                                               float* __restrict__ out) {
    int wid = (blockIdx.x * 256 + threadIdx.x) >> 6;
    int lane = threadIdx.x & 63;
    int g = lane >> 4, c = lane & 15;
    int d0 = wid * 4 + g;
    if (d0 < N_NODES) {
        int lo = dstart[d0], hi = dstart[d0 + 1];
        float acc = out[(size_t)d0 * NCLS + c];
        int e = lo;
        for (; e + 2 <= hi; e += 2) {
            int2 m0 = sedge[e], m1 = sedge[e + 1];
            float v0 = bf2f(H2[((size_t)(m0.x >> 16) * N_NODES + (m0.x & 0xFFFF)) * NCLS + c]);
            float v1 = bf2f(H2[((size_t)(m1.x >> 16) * N_NODES + (m1.x & 0xFFFF)) * NCLS + c]);
            acc = fmaf(__int_as_float(m0.y), v0, acc);
            acc = fmaf(__int_as_float(m1.y), v1, acc);
        }
        if (e < hi) {
            int2 m = sedge[e];
            float v = bf2f(H2[((size_t)(m.x >> 16) * N_NODES + (m.x & 0xFFFF)) * NCLS + c]);
            acc = fmaf(__int_as_float(m.y), v, acc);
        }
        out[(size_t)d0 * NCLS + c] = acc;
    }
}

extern "C" void kernel_launch(void* const* d_in, const int* in_sizes, int n_in,
                              void* d_out, int out_size, void* d_ws, size_t ws_size,
                              hipStream_t stream) {
    const int* ei    = (const int*)d_in[0];
    const int* et    = (const int*)d_in[1];
    const float* x   = (const float*)d_in[2];
    const float* W1  = (const float*)d_in[3];
    const float* r1  = (const float*)d_in[4];
    const float* b1  = (const float*)d_in[5];
    const float* W2  = (const float*)d_in[6];
    const float* r2  = (const float*)d_in[7];
    const float* b2  = (const float*)d_in[8];
    float* out = (float*)d_out;

    int E = in_sizes[0] / 2;
    const int* srcp = ei;
    const int* dstp = ei + E;

    float* cnt    = (float*)d_ws;
    int*   dcnt   = (int*)(cnt + (size_t)NREL * N_NODES);
    int*   dstart = dcnt + N_NODES;
    int*   cursor = dstart + 50004;
    int*   bsum   = cursor + N_NODES;
    int2*  sedge  = (int2*)(bsum + 100);
    ushort* xb    = (ushort*)(sedge + E);
    ushort* WbT1  = xb + (size_t)N_NODES * HID;
    ushort* WbT2  = WbT1 + 17 * HID * HID;
    ushort* H1    = WbT2 + 17 * NCLS * HID;
    ushort* H2    = H1 + (size_t)NREL * N_NODES * HID;
    ushort* X1m   = H2 + (size_t)NREL * N_NODES * NCLS;

    hipMemsetAsync(cnt, 0, ((size_t)NREL * N_NODES + N_NODES) * sizeof(int), stream);

    int eb = (E + 255) / 256;
    int cvtThreads = N_NODES * HID / 4 + 17 * HID * HID + 17 * NCLS * HID;

    cvt_k<<<(cvtThreads + 255) / 256, 256, 0, stream>>>(x, W1, r1, W2, r2, xb, WbT1, WbT2);
    cnt_k<<<eb, 256, 0, stream>>>(dstp, et, cnt, dcnt, E);
    scan1_k<<<NSB, 256, 0, stream>>>(dcnt, bsum);
    scan2_k<<<1, 128, 0, stream>>>(bsum, dstart, E);
    scan3_k<<<NSB, 256, 0, stream>>>(dcnt, bsum, dstart, cursor);
    scat_k<<<eb, 256, 0, stream>>>(srcp, dstp, et, cnt, cursor, sedge, E);

    trans1_k<<<(3 * NTILES + 3) / 4, 256, 0, stream>>>(xb, WbT1, b1, H1, X1m);
    edge1_k<<<(N_NODES + 3) / 4, 256, 0, stream>>>(sedge, dstart, H1, X1m);
    trans2_k<<<(3 * NTILES + 3) / 4, 256, 0, stream>>>(X1m, WbT2, b2, H2, out);
    edge2_k<<<(N_NODES / 4 + 3) / 4, 256, 0, stream>>>(sedge, dstart, H2, out);
}

// Round 9
// 300.207 us; speedup vs baseline: 9.9887x; 1.1658x over previous
//
#include <hip/hip_runtime.h>
#include <hip/hip_bf16.h>

#define N_NODES 50000
#define NREL 16
#define HID 64
#define NCLS 16
#define NTILES 3125            // N_NODES / 16
#define NBKT (N_NODES * NREL)  // 800000 buckets (dst*16 + rel)
#define SB 2048                // scan elems per block
#define NSB ((NBKT + SB - 1) / SB)  // 391

typedef __attribute__((ext_vector_type(8))) short bf16x8;
typedef __attribute__((ext_vector_type(4))) float f32x4;

static __device__ __forceinline__ unsigned short f2bf(float f) {
    __hip_bfloat16 h = __float2bfloat16(f);
    return *reinterpret_cast<unsigned short*>(&h);
}
static __device__ __forceinline__ float bf2f(unsigned short u) {
    __hip_bfloat16 h;
    *reinterpret_cast<unsigned short*>(&h) = u;
    return __bfloat162float(h);
}

// ---------------------------------------------------------------------------
// ws layout:
//   bcnt/rstart i32[800020] (zeroed; scan3 converts counts -> prefix IN PLACE)
//   | rank i32[E] | bsum i32[512] | sedge int2[E] {src|(rel<<16), inv}
//   | xb bf16[50000*64] | WbT1 bf16[17*64*64] | WbT2 bf16[17*16*64]
//   | H1 bf16[16*50000*64]  SWIZZLED: row elem j holds col (j&3)*16+(j>>2)
//   | H2 bf16[16*50000*16] | X1m bf16[50000*64] (standard layout)
//   total ~153.8 MB
// ---------------------------------------------------------------------------

// K1: one atomic pass over buckets (dst*16+rel): count + per-edge rank
__global__ __launch_bounds__(256) void rank_k(const int* __restrict__ dstp,
                                              const int* __restrict__ et,
                                              int* __restrict__ bcnt,
                                              int* __restrict__ rank, int E) {
    int i = blockIdx.x * 256 + threadIdx.x;
    if (i < E) {
        int b = dstp[i] * NREL + et[i];
        rank[i] = atomicAdd(&bcnt[b], 1);
    }
}

// K2a: per-block sums of bcnt (2048 elems / block, 8 per thread)
__global__ __launch_bounds__(256) void scan1_k(const int* __restrict__ bcnt,
                                               int* __restrict__ bsum) {
    int b = blockIdx.x, t = threadIdx.x;
    int base = b * SB + t * 8;
    int s = 0;
#pragma unroll
    for (int j = 0; j < 8; ++j)
        if (base + j < NBKT) s += bcnt[base + j];
#pragma unroll
    for (int off = 1; off < 64; off <<= 1) s += __shfl_xor(s, off, 64);
    __shared__ int ws[4];
    if ((t & 63) == 0) ws[t >> 6] = s;
    __syncthreads();
    if (t == 0) bsum[b] = ws[0] + ws[1] + ws[2] + ws[3];
}

// K2b: exclusive scan of bsum[NSB] (one 512-thread block); rstart[NBKT] = E
__global__ __launch_bounds__(512) void scan2_k(int* __restrict__ bsum,
                                               int* __restrict__ rstart, int E) {
    __shared__ int ts[512];
    int t = threadIdx.x;
    int v = (t < NSB) ? bsum[t] : 0;
    ts[t] = v;
    __syncthreads();
    int acc = v;
    for (int off = 1; off < 512; off <<= 1) {
        int u = (t >= off) ? ts[t - off] : 0;
        __syncthreads();
        acc += u;
        ts[t] = acc;
        __syncthreads();
    }
    if (t < NSB) bsum[t] = acc - v;
    if (t == 0) rstart[NBKT] = E;
}

// K2c: per-block exclusive scan, IN PLACE (bcnt -> rstart). Each thread
// reads its 8 values into registers first, so the overwrite is hazard-free.
__global__ __launch_bounds__(256) void scan3_k(int* __restrict__ bcnt,
                                               const int* __restrict__ bsum) {
    int b = blockIdx.x, t = threadIdx.x;
    int base = b * SB + t * 8;
    int a[8];
    int s = 0;
#pragma unroll
    for (int j = 0; j < 8; ++j) {
        a[j] = (base + j < NBKT) ? bcnt[base + j] : 0;
        s += a[j];
    }
    __shared__ int ts[256];
    ts[t] = s;
    __syncthreads();
    int acc = s;
    for (int off = 1; off < 256; off <<= 1) {
        int u = (t >= off) ? ts[t - off] : 0;
        __syncthreads();
        acc += u;
        ts[t] = acc;
        __syncthreads();
    }
    int run = bsum[b] + (acc - s);
#pragma unroll
    for (int j = 0; j < 8; ++j) {
        if (base + j < NBKT) bcnt[base + j] = run;
        run += a[j];
    }
}

// K3: atomic-free scatter: slot = rstart[bucket] + rank; inv from prefix diff
__global__ __launch_bounds__(256) void scat_k(const int* __restrict__ srcp,
                                              const int* __restrict__ dstp,
                                              const int* __restrict__ et,
                                              const int* __restrict__ rank,
                                              const int* __restrict__ rstart,
                                              int2* __restrict__ sedge, int E) {
    int i = blockIdx.x * 256 + threadIdx.x;
    if (i < E) {
        int r = et[i];
        int b = dstp[i] * NREL + r;
        int lo = rstart[b], hi = rstart[b + 1];
        int p = lo + rank[i];
        float inv = 1.0f / (float)(hi - lo);
        sedge[p] = make_int2(srcp[i] | (r << 16), __float_as_int(inv));
    }
}

// K4: convert x -> bf16, build transposed bf16 weights (task 16 = root)
__global__ __launch_bounds__(256) void cvt_k(const float* __restrict__ x,
                                             const float* __restrict__ W1,
                                             const float* __restrict__ root1,
                                             const float* __restrict__ W2,
                                             const float* __restrict__ root2,
                                             ushort* __restrict__ xb,
                                             ushort* __restrict__ WbT1,
                                             ushort* __restrict__ WbT2) {
    int i = blockIdx.x * 256 + threadIdx.x;
    if (i < N_NODES * HID / 4) {
        float4 v = ((const float4*)x)[i];
        ushort4 o;
        o.x = f2bf(v.x); o.y = f2bf(v.y); o.z = f2bf(v.z); o.w = f2bf(v.w);
        ((ushort4*)xb)[i] = o;
    } else if (i < N_NODES * HID / 4 + 17 * HID * HID) {
        int j = i - N_NODES * HID / 4;
        int t = j >> 12;
        int rem = j & 4095;
        int n = rem >> 6, k = rem & 63;
        float v = (t < 16) ? W1[(size_t)t * HID * HID + k * HID + n]
                           : root1[k * HID + n];
        WbT1[j] = f2bf(v);
    } else {
        int j = i - N_NODES * HID / 4 - 17 * HID * HID;
        if (j < 17 * NCLS * HID) {
            int t = j >> 10;
            int rem = j & 1023;
            int n = rem >> 6, k = rem & 63;
            float v = (t < 16) ? W2[(size_t)t * HID * NCLS + k * NCLS + n]
                               : root2[k * NCLS + n];
            WbT2[j] = f2bf(v);
        }
    }
}

// K5: MFMA transform 1, task-split into 3 groups (6+6+5 incl root).
// H1 stores SWIZZLED as ushort4 (8B/lane): Ht[node*64 + mr*4 + nt].
__global__ __launch_bounds__(256) void trans1_k(const ushort* __restrict__ xb,
                                                const ushort* __restrict__ WbT1,
                                                const float* __restrict__ b1,
                                                ushort* __restrict__ H1,
                                                ushort* __restrict__ X1m) {
    int wid = (blockIdx.x * 256 + threadIdx.x) >> 6;
    int lane = threadIdx.x & 63;
    int grp = wid / NTILES;
    if (grp >= 3) return;
    int tile = wid - grp * NTILES;
    int n0 = tile * 16;
    int mr = lane & 15;   // A row / D col
    int kq = lane >> 4;   // k-quad

    const bf16x8* arow = (const bf16x8*)(xb + (size_t)(n0 + mr) * HID + kq * 8);
    bf16x8 a0 = arow[0];
    bf16x8 a1 = arow[4];

    int t0 = grp * 6;
    int t1 = (grp == 2) ? 17 : (t0 + 6);

    const ushort* wbase = WbT1 + (size_t)mr * HID + kq * 8;
    for (int t = t0; t < t1; ++t) {
        const ushort* wt = wbase + (size_t)t * HID * HID;
        f32x4 acc[4];
#pragma unroll
        for (int nt = 0; nt < 4; ++nt) {
            bf16x8 b0 = *(const bf16x8*)(wt + nt * 1024);
            bf16x8 bv = *(const bf16x8*)(wt + nt * 1024 + 32);
            f32x4 c = {0.f, 0.f, 0.f, 0.f};
            c = __builtin_amdgcn_mfma_f32_16x16x32_bf16(a0, b0, c, 0, 0, 0);
            c = __builtin_amdgcn_mfma_f32_16x16x32_bf16(a1, bv, c, 0, 0, 0);
            acc[nt] = c;
        }
        if (t < 16) {
            ushort* Ht = H1 + (size_t)t * N_NODES * HID;
#pragma unroll
            for (int r = 0; r < 4; ++r) {
                int node = n0 + kq * 4 + r;  // D row = quad*4+reg
                ushort4 o;
                o.x = f2bf(acc[0][r]); o.y = f2bf(acc[1][r]);
                o.z = f2bf(acc[2][r]); o.w = f2bf(acc[3][r]);
                *(ushort4*)(Ht + (size_t)node * HID + mr * 4) = o;
            }
        } else {
#pragma unroll
            for (int nt = 0; nt < 4; ++nt) {
                float bias = b1[nt * 16 + mr];
#pragma unroll
                for (int r = 0; r < 4; ++r) {
                    int node = n0 + kq * 4 + r;
                    X1m[(size_t)node * HID + nt * 16 + mr] =
                        f2bf(acc[nt][r] + bias);
                }
            }
        }
    }
}

// K6: layer-1 gather. Wave owns dst node; lane j covers col (j&3)*16+(j>>2)
// (H1 swizzle). CSR bounds come straight from rstart (dst*16 .. dst*16+16).
__global__ __launch_bounds__(256) void edge1_k(const int2* __restrict__ sedge,
                                               const int* __restrict__ rstart,
                                               const ushort* __restrict__ H1,
                                               ushort* __restrict__ X1m) {
    int wid = (blockIdx.x * 256 + threadIdx.x) >> 6;
    int lane = threadIdx.x & 63;
    if (wid >= N_NODES) return;
    int col = (lane & 3) * 16 + (lane >> 2);
    int lo = rstart[wid << 4], hi = rstart[(wid + 1) << 4];
    float acc = bf2f(X1m[(size_t)wid * HID + col]);
    int e = lo;
    for (; e + 4 <= hi; e += 4) {
        int2 m0 = sedge[e], m1 = sedge[e + 1], m2 = sedge[e + 2], m3 = sedge[e + 3];
        float v0 = bf2f(H1[((size_t)(m0.x >> 16) * N_NODES + (m0.x & 0xFFFF)) * HID + lane]);
        float v1 = bf2f(H1[((size_t)(m1.x >> 16) * N_NODES + (m1.x & 0xFFFF)) * HID + lane]);
        float v2 = bf2f(H1[((size_t)(m2.x >> 16) * N_NODES + (m2.x & 0xFFFF)) * HID + lane]);
        float v3 = bf2f(H1[((size_t)(m3.x >> 16) * N_NODES + (m3.x & 0xFFFF)) * HID + lane]);
        acc = fmaf(__int_as_float(m0.y), v0, acc);
        acc = fmaf(__int_as_float(m1.y), v1, acc);
        acc = fmaf(__int_as_float(m2.y), v2, acc);
        acc = fmaf(__int_as_float(m3.y), v3, acc);
    }
    for (; e < hi; ++e) {
        int2 m = sedge[e];
        float v = bf2f(H1[((size_t)(m.x >> 16) * N_NODES + (m.x & 0xFFFF)) * HID + lane]);
        acc = fmaf(__int_as_float(m.y), v, acc);
    }
    X1m[(size_t)wid * HID + col] = f2bf(fmaxf(acc, 0.f));  // relu folded
}

// K7: MFMA transform 2, task-split into 3 groups. A = relu'd X1m (standard).
__global__ __launch_bounds__(256) void trans2_k(const ushort* __restrict__ X1m,
                                                const ushort* __restrict__ WbT2,
                                                const float* __restrict__ b2,
                                                ushort* __restrict__ H2,
                                                float* __restrict__ out) {
    int wid = (blockIdx.x * 256 + threadIdx.x) >> 6;
    int lane = threadIdx.x & 63;
    int grp = wid / NTILES;
    if (grp >= 3) return;
    int tile = wid - grp * NTILES;
    int n0 = tile * 16;
    int mr = lane & 15, kq = lane >> 4;
    const bf16x8* arow = (const bf16x8*)(X1m + (size_t)(n0 + mr) * HID + kq * 8);
    bf16x8 a0 = arow[0];
    bf16x8 a1 = arow[4];
    int t0 = grp * 6;
    int t1 = (grp == 2) ? 17 : (t0 + 6);
    const ushort* wbase = WbT2 + (size_t)mr * HID + kq * 8;
    for (int t = t0; t < t1; ++t) {
        const ushort* wt = wbase + (size_t)t * NCLS * HID;
        bf16x8 b0 = *(const bf16x8*)(wt);
        bf16x8 bv = *(const bf16x8*)(wt + 32);
        f32x4 c = {0.f, 0.f, 0.f, 0.f};
        c = __builtin_amdgcn_mfma_f32_16x16x32_bf16(a0, b0, c, 0, 0, 0);
        c = __builtin_amdgcn_mfma_f32_16x16x32_bf16(a1, bv, c, 0, 0, 0);
        if (t < 16) {
            ushort* Ht = H2 + (size_t)t * N_NODES * NCLS;
#pragma unroll
            for (int r = 0; r < 4; ++r) {
                int node = n0 + kq * 4 + r;
                Ht[(size_t)node * NCLS + mr] = f2bf(c[r]);
            }
        } else {
            float bias = b2[mr];
#pragma unroll
            for (int r = 0; r < 4; ++r) {
                int node = n0 + kq * 4 + r;
                out[(size_t)node * NCLS + mr] = c[r] + bias;
            }
        }
    }
}

// K8: layer-2 gather. 4 dst per wave (16-lane groups, lane = class).
__global__ __launch_bounds__(256) void edge2_k(const int2* __restrict__ sedge,
                                               const int* __restrict__ rstart,
                                               const ushort* __restrict__ H2,
                                               float* __restrict__ out) {
    int wid = (blockIdx.x * 256 + threadIdx.x) >> 6;
    int lane = threadIdx.x & 63;
    int g = lane >> 4, c = lane & 15;
    int d0 = wid * 4 + g;
    if (d0 < N_NODES) {
        int lo = rstart[d0 << 4], hi = rstart[(d0 + 1) << 4];
        float acc = out[(size_t)d0 * NCLS + c];
        int e = lo;
        for (; e + 2 <= hi; e += 2) {
            int2 m0 = sedge[e], m1 = sedge[e + 1];
            float v0 = bf2f(H2[((size_t)(m0.x >> 16) * N_NODES + (m0.x & 0xFFFF)) * NCLS + c]);
            float v1 = bf2f(H2[((size_t)(m1.x >> 16) * N_NODES + (m1.x & 0xFFFF)) * NCLS + c]);
            acc = fmaf(__int_as_float(m0.y), v0, acc);
            acc = fmaf(__int_as_float(m1.y), v1, acc);
        }
        if (e < hi) {
            int2 m = sedge[e];
            float v = bf2f(H2[((size_t)(m.x >> 16) * N_NODES + (m.x & 0xFFFF)) * NCLS + c]);
            acc = fmaf(__int_as_float(m.y), v, acc);
        }
        out[(size_t)d0 * NCLS + c] = acc;
    }
}

extern "C" void kernel_launch(void* const* d_in, const int* in_sizes, int n_in,
                              void* d_out, int out_size, void* d_ws, size_t ws_size,
                              hipStream_t stream) {
    const int* ei    = (const int*)d_in[0];
    const int* et    = (const int*)d_in[1];
    const float* x   = (const float*)d_in[2];
    const float* W1  = (const float*)d_in[3];
    const float* r1  = (const float*)d_in[4];
    const float* b1  = (const float*)d_in[5];
    const float* W2  = (const float*)d_in[6];
    const float* r2  = (const float*)d_in[7];
    const float* b2  = (const float*)d_in[8];
    float* out = (float*)d_out;

    int E = in_sizes[0] / 2;
    const int* srcp = ei;
    const int* dstp = ei + E;

    int*   bcnt   = (int*)d_ws;                 // doubles as rstart after scan3
    int*   rank   = bcnt + (NBKT + 20);
    int*   bsum   = rank + E;                   // 512 ints (NSB=391 used)
    int2*  sedge  = (int2*)(bsum + 512);
    ushort* xb    = (ushort*)(sedge + E);
    ushort* WbT1  = xb + (size_t)N_NODES * HID;
    ushort* WbT2  = WbT1 + 17 * HID * HID;
    ushort* H1    = WbT2 + 17 * NCLS * HID;
    ushort* H2    = H1 + (size_t)NREL * N_NODES * HID;
    ushort* X1m   = H2 + (size_t)NREL * N_NODES * NCLS;
    int*   rstart = bcnt;                       // alias (in-place scan)

    hipMemsetAsync(bcnt, 0, (NBKT + 20) * sizeof(int), stream);

    int eb = (E + 255) / 256;
    int cvtThreads = N_NODES * HID / 4 + 17 * HID * HID + 17 * NCLS * HID;

    cvt_k<<<(cvtThreads + 255) / 256, 256, 0, stream>>>(x, W1, r1, W2, r2, xb, WbT1, WbT2);
    rank_k<<<eb, 256, 0, stream>>>(dstp, et, bcnt, rank, E);
    scan1_k<<<NSB, 256, 0, stream>>>(bcnt, bsum);
    scan2_k<<<1, 512, 0, stream>>>(bsum, rstart, E);
    scan3_k<<<NSB, 256, 0, stream>>>(bcnt, bsum);
    scat_k<<<eb, 256, 0, stream>>>(srcp, dstp, et, rank, rstart, sedge, E);

    trans1_k<<<(3 * NTILES + 3) / 4, 256, 0, stream>>>(xb, WbT1, b1, H1, X1m);
    edge1_k<<<(N_NODES + 3) / 4, 256, 0, stream>>>(sedge, rstart, H1, X1m);
    trans2_k<<<(3 * NTILES + 3) / 4, 256, 0, stream>>>(X1m, WbT2, b2, H2, out);
    edge2_k<<<(N_NODES / 4 + 3) / 4, 256, 0, stream>>>(sedge, rstart, H2, out);
}